// Round 6
// baseline (359.406 us; speedup 1.0000x reference)
//
#include <hip/hip_runtime.h>
#include <hip/hip_bf16.h>

typedef __hip_bfloat16 bf16;
using bf16x8 = __attribute__((ext_vector_type(8))) short;
using f32x4  = __attribute__((ext_vector_type(4))) float;
using f32x16 = __attribute__((ext_vector_type(16))) float;
using u32x4  = __attribute__((ext_vector_type(4))) unsigned int;

#define TSEQ 2048
#define NH   16
#define HD   64
#define NC   1024
#define DFF  4096
#define NROWS 4096   // B*T

__device__ __forceinline__ void load_lds16(const bf16* g, bf16* l) {
  __builtin_amdgcn_global_load_lds(
      (const __attribute__((address_space(1))) unsigned int*)g,
      (__attribute__((address_space(3))) unsigned int*)l, 16, 0, 0);
}

__device__ __forceinline__ float b2f(short s) {
  unsigned int u = ((unsigned int)(unsigned short)s) << 16;
  return __builtin_bit_cast(float, u);
}

// pack two f32 -> two bf16 (RNE), single instruction; dst.lo = a, dst.hi = b
__device__ __forceinline__ unsigned cvtpk(float a, float b) {
  unsigned r;
  asm("v_cvt_pk_bf16_f32 %0, %1, %2" : "=v"(r) : "v"(a), "v"(b));
  return r;
}

// v_permlane32_swap_b32 vdst, src: vdst[32:63] <-> src[0:31]
__device__ __forceinline__ void pl32swap(unsigned &d, unsigned &s) {
  asm("v_permlane32_swap_b32 %0, %1" : "+v"(d), "+v"(s));
}

// tanh-approx GELU via hw exp; |err| < ~1e-3 (vs exact-erf reference)
__device__ __forceinline__ float gelu_f(float x) {
  float u = 0.7978845608028654f * fmaf(0.044715f * x, x * x, x);
  float e = __expf(2.0f * u);
  float t = 1.0f - 2.0f / (e + 1.0f);   // tanh(u)
  return 0.5f * x * (1.0f + t);
}

// ---------------- LayerNorm (fp32 in) -> bf16 out ----------------
__global__ __launch_bounds__(256)
void ln_cast_kernel(const float* __restrict__ x, const float* __restrict__ g,
                    const float* __restrict__ b, bf16* __restrict__ out) {
  int row = blockIdx.x, tid = threadIdx.x;
  const float4 v = ((const float4*)(x + (size_t)row * NC))[tid];
  float s  = v.x + v.y + v.z + v.w;
  float s2 = v.x*v.x + v.y*v.y + v.z*v.z + v.w*v.w;
#pragma unroll
  for (int m = 1; m < 64; m <<= 1) { s += __shfl_xor(s, m); s2 += __shfl_xor(s2, m); }
  __shared__ float rs[4], rs2[4];
  if ((tid & 63) == 0) { rs[tid >> 6] = s; rs2[tid >> 6] = s2; }
  __syncthreads();
  s  = rs[0] + rs[1] + rs[2] + rs[3];
  s2 = rs2[0] + rs2[1] + rs2[2] + rs2[3];
  float mu   = s * (1.0f / NC);
  float var  = s2 * (1.0f / NC) - mu * mu;
  float rstd = rsqrtf(var + 1e-5f);
  const float4 gv = ((const float4*)g)[tid];
  const float4 bv = ((const float4*)b)[tid];
  bf16* o = out + (size_t)row * NC + tid * 4;
  o[0] = __float2bfloat16((v.x - mu) * rstd * gv.x + bv.x);
  o[1] = __float2bfloat16((v.y - mu) * rstd * gv.y + bv.y);
  o[2] = __float2bfloat16((v.z - mu) * rstd * gv.z + bv.z);
  o[3] = __float2bfloat16((v.w - mu) * rstd * gv.w + bv.w);
}

// ---- x2 = x + bo + P0 + P1 (bf16 partials); then LN(x2) -> xn2 (fused) ----
__global__ __launch_bounds__(256)
void wo_ln_kernel(const float* __restrict__ x, const float* __restrict__ bo,
                  const bf16* __restrict__ P, const float* __restrict__ g,
                  const float* __restrict__ bln, float* __restrict__ x2,
                  bf16* __restrict__ xn2) {
  int row = blockIdx.x, tid = threadIdx.x;
  size_t base = (size_t)row * NC + tid * 4;
  const float4 xv = *(const float4*)(x + base);
  const float4 bv = ((const float4*)bo)[tid];
  short4 p0 = *(const short4*)((const short*)P + base);
  short4 p1 = *(const short4*)((const short*)P + (size_t)NROWS * NC + base);
  float v0 = xv.x + bv.x + b2f(p0.x) + b2f(p1.x);
  float v1 = xv.y + bv.y + b2f(p0.y) + b2f(p1.y);
  float v2 = xv.z + bv.z + b2f(p0.z) + b2f(p1.z);
  float v3 = xv.w + bv.w + b2f(p0.w) + b2f(p1.w);
  float4 ov = {v0, v1, v2, v3};
  *(float4*)(x2 + base) = ov;
  float s  = v0 + v1 + v2 + v3;
  float s2 = v0*v0 + v1*v1 + v2*v2 + v3*v3;
#pragma unroll
  for (int m = 1; m < 64; m <<= 1) { s += __shfl_xor(s, m); s2 += __shfl_xor(s2, m); }
  __shared__ float rs[4], rs2[4];
  if ((tid & 63) == 0) { rs[tid >> 6] = s; rs2[tid >> 6] = s2; }
  __syncthreads();
  s  = rs[0] + rs[1] + rs[2] + rs[3];
  s2 = rs2[0] + rs2[1] + rs2[2] + rs2[3];
  float mu   = s * (1.0f / NC);
  float var  = s2 * (1.0f / NC) - mu * mu;
  float rstd = rsqrtf(var + 1e-5f);
  const float4 gv = ((const float4*)g)[tid];
  const float4 lv = ((const float4*)bln)[tid];
  bf16* o = xn2 + base;
  o[0] = __float2bfloat16((v0 - mu) * rstd * gv.x + lv.x);
  o[1] = __float2bfloat16((v1 - mu) * rstd * gv.y + lv.y);
  o[2] = __float2bfloat16((v2 - mu) * rstd * gv.z + lv.z);
  o[3] = __float2bfloat16((v3 - mu) * rstd * gv.w + lv.w);
}

// ---- d_out = x2 + b2 + sum of 4 bf16 partials ----
__global__ __launch_bounds__(256)
void w2_final_kernel(const float* __restrict__ x2, const float* __restrict__ b2,
                     const bf16* __restrict__ P, float* __restrict__ out) {
  int row = blockIdx.x, tid = threadIdx.x;
  size_t base = (size_t)row * NC + tid * 4;
  const float4 xv = *(const float4*)(x2 + base);
  const float4 bv = ((const float4*)b2)[tid];
  float a0 = xv.x + bv.x, a1 = xv.y + bv.y, a2 = xv.z + bv.z, a3 = xv.w + bv.w;
#pragma unroll
  for (int z = 0; z < 4; ++z) {
    short4 p = *(const short4*)((const short*)P + (size_t)z * NROWS * NC + base);
    a0 += b2f(p.x); a1 += b2f(p.y); a2 += b2f(p.z); a3 += b2f(p.w);
  }
  float4 ov = {a0, a1, a2, a3};
  *(float4*)(out + base) = ov;
}

// ---------------- all weight transposes in one launch ----------------
__global__ __launch_bounds__(256)
void transpose_all_kernel(const float* __restrict__ Wq, const float* __restrict__ Wk,
                          const float* __restrict__ Wv, const float* __restrict__ Wo,
                          const float* __restrict__ W1, const float* __restrict__ W2,
                          bf16* __restrict__ WqkvoT, bf16* __restrict__ W1T,
                          bf16* __restrict__ W2T) {
  int bid = blockIdx.x;
  const float* W; bf16* Wt; int K, N, nx, tile;
  if (bid < 4096) {
    int z = bid >> 10; tile = bid & 1023;
    W = (z == 0) ? Wq : (z == 1) ? Wk : (z == 2) ? Wv : Wo;
    Wt = WqkvoT + (size_t)z * NC * NC; K = NC; N = NC; nx = 32;
  } else if (bid < 8192) {
    tile = bid - 4096; W = W1; Wt = W1T; K = NC; N = DFF; nx = 128;
  } else {
    tile = bid - 8192; W = W2; Wt = W2T; K = DFF; N = NC; nx = 32;
  }
  int n0 = (tile % nx) * 32, k0 = (tile / nx) * 32;
  __shared__ float t[32][33];
  int tx = threadIdx.x, ty = threadIdx.y;  // 32 x 8
#pragma unroll
  for (int i = 0; i < 4; ++i)
    t[ty + i * 8][tx] = W[(size_t)(k0 + ty + i * 8) * N + n0 + tx];
  __syncthreads();
#pragma unroll
  for (int i = 0; i < 4; ++i)
    Wt[(size_t)(n0 + ty + i * 8) * K + k0 + tx] = __float2bfloat16(t[tx][ty + i * 8]);
}

// ---------------- GEMM v3: 256x256 block, 8 waves, depth-3 pipelined staging -------
// C(MxN) = A(MxK,bf16) @ Bt(NxK,bf16)^T. BK=32, 4 rotating LDS buffers (128KB).
// LDS holds tiles in FRAGMENT-SLOT order (slot = ks*512 + row*2 + khalf, 16B each):
//  - global_load_lds dest is linear (wave-uniform base + lane*16) as HW requires;
//    the permutation is folded into the per-lane global SOURCE address.
//  - every ds_read_b128 is a wave-linear 1KB block -> bank-conflict-free.
// Sync per K-tile: s_waitcnt vmcnt(8) (tiles t+1,t+2 stay in flight) + raw s_barrier;
// loads cross barriers (T3/T4). Wave tile 128x64 = 4x2 of 32x32; 16 MFMA + 12
// ds_read_b128 per tile; setprio(1) around MFMA cluster (T5).
#define MODE_GELU 4
#define MODE_QKV  5
#define MODE_PART 6

template <int MODE>
__global__ __launch_bounds__(512, 2)
void gemm256(const bf16* __restrict__ A, const bf16* __restrict__ Bt,
             const float* __restrict__ bias, const float* __restrict__ bias2,
             const float* __restrict__ bias3,
             void* __restrict__ outp, void* __restrict__ out2, void* __restrict__ out3,
             int M, int N, int K, int KS) {
  __shared__ bf16 lds[65536];   // A: 4 bufs x 8192 elems; B: +32768
  int tid  = threadIdx.x;
  int w    = tid >> 6;
  int lane = tid & 63;
  int l31  = lane & 31;
  int kb   = lane >> 5;          // k-half of fragment
  int wm   = w >> 2, wn = w & 3; // 2x4 wave grid; wave tile 128x64

  // block swizzle (GROUP_M = 4, col-major within group)
  int gN = gridDim.x, gM = gridDim.y;
  int pid = blockIdx.y * gN + blockIdx.x;
  int npg = 4 * gN;
  int gid = pid / npg;
  int fm  = gid * 4;
  int gsz = min(gM - fm, 4);
  int bm = (fm + (pid % gsz)) * 256;
  int bn = ((pid % npg) / gsz) * 256;
  int k_beg = blockIdx.z * KS;

  // staging: wave w, instr j in {0,1} per matrix; lane l sources
  // row = w*32 + (l>>1), k-offset = j*16 + (l&1)*8 (frag-slot order in LDS)
  int srow  = w * 32 + (lane >> 1);
  int skoff = (lane & 1) * 8;
  const bf16* sA[2]; const bf16* sB[2];
#pragma unroll
  for (int j = 0; j < 2; ++j) {
    sA[j] = A  + (size_t)(bm + srow) * K + k_beg + j * 16 + skoff;
    sB[j] = Bt + (size_t)(bn + srow) * K + k_beg + j * 16 + skoff;
  }

  auto stage = [&](int t) {
    int b = t & 3;
    bf16* dA = &lds[b * 8192];
    bf16* dB = &lds[32768 + b * 8192];
    int koff = t * 32;
#pragma unroll
    for (int j = 0; j < 2; ++j) {
      load_lds16(sA[j] + koff, dA + (j * 512 + w * 64) * 8);
      load_lds16(sB[j] + koff, dB + (j * 512 + w * 64) * 8);
    }
  };

  f32x16 acc[4][2];
#pragma unroll
  for (int mi = 0; mi < 4; ++mi)
#pragma unroll
    for (int ni = 0; ni < 2; ++ni)
#pragma unroll
      for (int r = 0; r < 16; ++r) acc[mi][ni][r] = 0.f;

  int NT = KS >> 5;
  stage(0); stage(1); stage(2);   // depth-3 prologue (12 loads/wave in flight)

  for (int t = 0; t < NT; ++t) {
    // own tile-t loads retired; each wave passing the barrier implies the same,
    // so after the barrier ALL tile-t data is in LDS. Tiles t+1,t+2 stay in flight.
    if (t < NT - 2)       asm volatile("s_waitcnt vmcnt(8)" ::: "memory");
    else if (t == NT - 2) asm volatile("s_waitcnt vmcnt(4)" ::: "memory");
    else                  asm volatile("s_waitcnt vmcnt(0)" ::: "memory");
    __builtin_amdgcn_s_barrier();
    asm volatile("" ::: "memory");
    if (t + 3 < NT) stage(t + 3);   // into buf (t+3)&3 == (t-1)&3, freed by barrier

    const bf16* bufA = &lds[(t & 3) * 8192];
    const bf16* bufB = &lds[32768 + (t & 3) * 8192];
    bf16x8 af[2][4], bfr[2][2];
#pragma unroll
    for (int ks = 0; ks < 2; ++ks) {
#pragma unroll
      for (int mi = 0; mi < 4; ++mi)
        af[ks][mi] = *(const bf16x8*)&bufA[(ks * 512 + (wm * 128 + mi * 32 + l31) * 2 + kb) * 8];
#pragma unroll
      for (int ni = 0; ni < 2; ++ni)
        bfr[ks][ni] = *(const bf16x8*)&bufB[(ks * 512 + (wn * 64 + ni * 32 + l31) * 2 + kb) * 8];
    }
    __builtin_amdgcn_s_setprio(1);
#pragma unroll
    for (int ks = 0; ks < 2; ++ks)
#pragma unroll
      for (int mi = 0; mi < 4; ++mi)
#pragma unroll
        for (int ni = 0; ni < 2; ++ni)
          acc[mi][ni] = __builtin_amdgcn_mfma_f32_32x32x16_bf16(af[ks][mi], bfr[ks][ni], acc[mi][ni], 0, 0, 0);
    __builtin_amdgcn_s_setprio(0);
  }

  // ---- epilogues (C: col = l31 of B-frag, row = (reg&3)+8*(reg>>2)+4*kb) ----
  if (MODE == MODE_PART) {
    bf16* dst = (bf16*)outp + (size_t)blockIdx.z * M * N;
#pragma unroll
    for (int mi = 0; mi < 4; ++mi)
#pragma unroll
      for (int ni = 0; ni < 2; ++ni) {
        int col = bn + wn * 64 + ni * 32 + l31;
#pragma unroll
        for (int reg = 0; reg < 16; ++reg) {
          int row = bm + wm * 128 + mi * 32 + (reg & 3) + 8 * (reg >> 2) + 4 * kb;
          dst[(size_t)row * N + col] = __float2bfloat16(acc[mi][ni][reg]);
        }
      }
  } else if (MODE == MODE_GELU) {
    float bcol[2];
#pragma unroll
    for (int ni = 0; ni < 2; ++ni) bcol[ni] = bias[bn + wn * 64 + ni * 32 + l31];
#pragma unroll
    for (int mi = 0; mi < 4; ++mi)
#pragma unroll
      for (int ni = 0; ni < 2; ++ni) {
        int col = bn + wn * 64 + ni * 32 + l31;
#pragma unroll
        for (int reg = 0; reg < 16; ++reg) {
          int row = bm + wm * 128 + mi * 32 + (reg & 3) + 8 * (reg >> 2) + 4 * kb;
          ((bf16*)outp)[(size_t)row * N + col] =
              __float2bfloat16(gelu_f(acc[mi][ni][reg] + bcol[ni]));
        }
      }
  } else {  // MODE_QKV: seg block-uniform; q -> (b,h,t,d); k -> Kf frag; v -> Vf frag
    int seg = bn >> 10;
    int c1b = (bn & (NC - 1)) + wn * 64;
    const float* bp = (seg == 0) ? bias : (seg == 1) ? bias2 : bias3;
    float bcol[2]; int hh[2], dd[2];
#pragma unroll
    for (int ni = 0; ni < 2; ++ni) {
      int c1 = c1b + ni * 32 + l31;
      bcol[ni] = bp[c1]; hh[ni] = c1 >> 6; dd[ni] = c1 & (HD - 1);
    }
    if (seg == 0) {
      bf16* dst = (bf16*)outp;
#pragma unroll
      for (int mi = 0; mi < 4; ++mi)
#pragma unroll
        for (int reg = 0; reg < 16; ++reg) {
          int row = bm + wm * 128 + mi * 32 + (reg & 3) + 8 * (reg >> 2) + 4 * kb;
          int bbi = row >> 11, t = row & (TSEQ - 1);
#pragma unroll
          for (int ni = 0; ni < 2; ++ni)
            dst[((size_t)(bbi * NH + hh[ni]) * TSEQ + t) * HD + dd[ni]] =
                __float2bfloat16(acc[mi][ni][reg] + bcol[ni]);
        }
    } else if (seg == 1) {
      // Kf[bh][kt(64)][ds(4)][lane(64)][8]
      bf16* dst = (bf16*)out2;
#pragma unroll
      for (int mi = 0; mi < 4; ++mi)
#pragma unroll
        for (int reg = 0; reg < 16; ++reg) {
          int row = bm + wm * 128 + mi * 32 + (reg & 3) + 8 * (reg >> 2) + 4 * kb;
          int bbi = row >> 11, t = row & (TSEQ - 1);
          int kt = t >> 5, lk = t & 31;
#pragma unroll
          for (int ni = 0; ni < 2; ++ni) {
            int d = dd[ni];
            size_t off = ((((size_t)(bbi * NH + hh[ni]) * 64 + kt) * 4 + (d >> 4)) * 64
                          + ((d >> 3) & 1) * 32 + lk) * 8 + (d & 7);
            dst[off] = __float2bfloat16(acc[mi][ni][reg] + bcol[ni]);
          }
        }
    } else {
      // Vf[bh][kt(64)][dt(2)][ks(2)][lane(64)][8]
      bf16* dst = (bf16*)out3;
#pragma unroll
      for (int mi = 0; mi < 4; ++mi)
#pragma unroll
        for (int reg = 0; reg < 16; ++reg) {
          int row = bm + wm * 128 + mi * 32 + (reg & 3) + 8 * (reg >> 2) + 4 * kb;
          int bbi = row >> 11, t = row & (TSEQ - 1);
          int kt = t >> 5, rem = t & 31;
          int ks = rem >> 4, hf = (rem >> 3) & 1, j = rem & 7;
#pragma unroll
          for (int ni = 0; ni < 2; ++ni) {
            int d = dd[ni];
            size_t off = (((((size_t)(bbi * NH + hh[ni]) * 64 + kt) * 2 + (d >> 5)) * 2 + ks) * 64
                          + hf * 32 + (d & 31)) * 8 + j;
            dst[off] = __float2bfloat16(acc[mi][ni][reg] + bcol[ni]);
          }
        }
    }
  }
}

// ---------------- Flash attention v6: swapped-QK^T 32x32, split-K x4, frag-layout K/V ----
__global__ __launch_bounds__(256)
void attn_kernel(const bf16* __restrict__ q, const bf16* __restrict__ kf,
                 const bf16* __restrict__ vf, bf16* __restrict__ out) {
  int id  = blockIdx.x;            // 0..2047
  int xcd = id & 7;
  int t   = id >> 3;               // per-XCD arrival index 0..255
  int bh  = xcd * 4 + (t & 3);
  int u   = t >> 2;                // 0..63
  int qt  = (u < 32) ? (2 * u) : (63 - 2 * (u - 32));
  int b = bh >> 4, h = bh & 15;

  int tid  = threadIdx.x;
  int w    = tid >> 6;             // split-K wave 0..3
  int lane = tid & 63;
  int l31  = lane & 31;
  int hh   = lane >> 5;            // 0/1
  int h8   = hh * 8;
  int base4 = hh * 4;

  const bf16* qp  = q  + (size_t)(b * NH + h) * TSEQ * HD;
  const bf16* kfb = kf + (size_t)bh * (64 * 4 * 64 * 8);   // 256KB per (b,h)
  const bf16* vfb = vf + (size_t)bh * (64 * 2 * 2 * 64 * 8);

  int q0 = qt * 32;

  // Q fragments (B-operand): lane holds Q[q0+l31][ds*16 + h8 .. +7]
  bf16x8 qf[4];
#pragma unroll
  for (int ds = 0; ds < 4; ++ds)
    qf[ds] = *(const bf16x8*)(qp + (size_t)(q0 + l31) * HD + ds * 16 + h8);

  f32x16 o0, o1;
#pragma unroll
  for (int r = 0; r < 16; ++r) { o0[r] = 0.f; o1[r] = 0.f; }
  float lacc = 0.f;

  bf16x8 a0, a1, a2, a3;           // K fragments (A-operand), pipelined

  auto step = [&](int kt, bool dg) {
    const bf16* vs = vfb + (size_t)kt * 2048 + lane * 8;
    bf16x8 v00 = *(const bf16x8*)(vs);            // dt0 ks0
    bf16x8 v01 = *(const bf16x8*)(vs + 512);      // dt0 ks1
    bf16x8 v10 = *(const bf16x8*)(vs + 1024);     // dt1 ks0
    bf16x8 v11 = *(const bf16x8*)(vs + 1536);     // dt1 ks1
    bf16x8 n0, n1, n2, n3;
    bool pf = !dg && (kt + 4 <= qt);
    if (pf) {
      const bf16* kn = kfb + (size_t)(kt + 4) * 2048 + lane * 8;
      n0 = *(const bf16x8*)(kn);
      n1 = *(const bf16x8*)(kn + 512);
      n2 = *(const bf16x8*)(kn + 1024);
      n3 = *(const bf16x8*)(kn + 1536);
    }

    f32x16 c;
#pragma unroll
    for (int r = 0; r < 16; ++r) c[r] = 0.f;
    c = __builtin_amdgcn_mfma_f32_32x32x16_bf16(a0, qf[0], c, 0, 0, 0);
    c = __builtin_amdgcn_mfma_f32_32x32x16_bf16(a1, qf[1], c, 0, 0, 0);
    c = __builtin_amdgcn_mfma_f32_32x32x16_bf16(a2, qf[2], c, 0, 0, 0);
    c = __builtin_amdgcn_mfma_f32_32x32x16_bf16(a3, qf[3], c, 0, 0, 0);

    float p[16];
    float ls = 0.f;
#pragma unroll
    for (int r = 0; r < 16; ++r) {
      float pv = exp2f(fmaf(c[r], 0.18033688011112042f, -11.541560327111707f));
      if (dg) {
        int krr = (r & 3) + 8 * (r >> 2) + base4;
        pv = (krr <= l31) ? pv : 0.f;
      }
      p[r] = pv;
      ls += pv;
    }
    lacc += ls;

    unsigned A0 = cvtpk(p[0],  p[1]),  C0 = cvtpk(p[4],  p[5]);
    unsigned B0 = cvtpk(p[2],  p[3]),  D0 = cvtpk(p[6],  p[7]);
    pl32swap(A0, C0); pl32swap(B0, D0);
    unsigned A1 = cvtpk(p[8],  p[9]),  C1 = cvtpk(p[12], p[13]);
    unsigned B1 = cvtpk(p[10], p[11]), D1 = cvtpk(p[14], p[15]);
    pl32swap(A1, C1); pl32swap(B1, D1);
    u32x4 w0v = {A0, B0, C0, D0};
    u32x4 w1v = {A1, B1, C1, D1};
    bf16x8 pa0 = __builtin_bit_cast(bf16x8, w0v);
    bf16x8 pa1 = __builtin_bit_cast(bf16x8, w1v);

    o0 = __builtin_amdgcn_mfma_f32_32x32x16_bf16(pa0, v00, o0, 0, 0, 0);
    o0 = __builtin_amdgcn_mfma_f32_32x32x16_bf16(pa1, v01, o0, 0, 0, 0);
    o1 = __builtin_amdgcn_mfma_f32_32x32x16_bf16(pa0, v10, o1, 0, 0, 0);
    o1 = __builtin_amdgcn_mfma_f32_32x32x16_bf16(pa1, v11, o1, 0, 0, 0);

    if (pf) { a0 = n0; a1 = n1; a2 = n2; a3 = n3; }
  };

  if (w <= qt) {
    const bf16* ka = kfb + (size_t)w * 2048 + lane * 8;
    a0 = *(const bf16x8*)(ka);
    a1 = *(const bf16x8*)(ka + 512);
    a2 = *(const bf16x8*)(ka + 1024);
    a3 = *(const bf16x8*)(ka + 1536);
    int diag = (w == (qt & 3)) ? 1 : 0;   // diag implies w <= qt
    int T = ((qt - w) >> 2) + 1 - diag;   // non-diag step count
    int kt = w;
    for (int i = 0; i < T; ++i, kt += 4) step(kt, false);
    if (diag) step(qt, true);
  }

  // ---- cross-wave combine: 2-round LDS tree (33-float stride: conflict-free) ----
  __shared__ float red[2][64][33];
  auto dump = [&](int slot) {
    float* d = &red[slot][lane][0];
#pragma unroll
    for (int r = 0; r < 16; ++r) { d[r] = o0[r]; d[16 + r] = o1[r]; }
    d[32] = lacc;
  };
  auto gather = [&](int slot) {
    const float* s = &red[slot][lane][0];
#pragma unroll
    for (int r = 0; r < 16; ++r) { o0[r] += s[r]; o1[r] += s[16 + r]; }
    lacc += s[32];
  };
  if (w >= 2) dump(w - 2);
  __syncthreads();
  if (w < 2) gather(w);
  __syncthreads();
  if (w == 1) dump(0);
  __syncthreads();
  if (w == 0) {
    gather(0);
    float ltot = lacc + __shfl_xor(lacc, 32);
    float linv = 1.0f / ltot;
#pragma unroll
    for (int r = 0; r < 16; ++r) {
      int qoff = (r & 3) + 8 * (r >> 2) + base4;
      float sc = __shfl(linv, qoff);
      size_t ob = ((size_t)(b * TSEQ + q0 + qoff)) * NC + h * HD + l31;
      out[ob]      = __float2bfloat16(o0[r] * sc);
      out[ob + 32] = __float2bfloat16(o1[r] * sc);
    }
  }
}

extern "C" void kernel_launch(void* const* d_in, const int* in_sizes, int n_in,
                              void* d_out, int out_size, void* d_ws, size_t ws_size,
                              hipStream_t stream) {
  const float* x     = (const float*)d_in[0];
  const float* ln1_g = (const float*)d_in[1];
  const float* ln1_b = (const float*)d_in[2];
  const float* Wq    = (const float*)d_in[3];
  const float* bq    = (const float*)d_in[4];
  const float* Wk    = (const float*)d_in[5];
  const float* bk    = (const float*)d_in[6];
  const float* Wv    = (const float*)d_in[7];
  const float* bv    = (const float*)d_in[8];
  const float* Wo    = (const float*)d_in[9];
  const float* bo    = (const float*)d_in[10];
  const float* ln2_g = (const float*)d_in[11];
  const float* ln2_b = (const float*)d_in[12];
  const float* W1    = (const float*)d_in[13];
  const float* b1    = (const float*)d_in[14];
  const float* W2    = (const float*)d_in[15];
  const float* b2    = (const float*)d_in[16];

  char* ws = (char*)d_ws;
  const size_t MB = 1u << 20;
  bf16* WqkvT = (bf16*)(ws + 0 * MB);   // 4x1024x1024 (q|k|v|o)
  bf16* W1T  = (bf16*)(ws + 8 * MB);    // 4096x1024
  bf16* W2T  = (bf16*)(ws + 16 * MB);   // 1024x4096
  bf16* xn1  = (bf16*)(ws + 24 * MB);   // 4096x1024
  bf16* qb   = (bf16*)(ws + 32 * MB);   // (b,h,t,d)        [dead after attn]
  bf16* kfB  = (bf16*)(ws + 40 * MB);   // K fragment layout [dead after attn]
  bf16* vfB  = (bf16*)(ws + 48 * MB);   // V fragment layout [dead after attn]
  bf16* att  = (bf16*)(ws + 56 * MB);   // 4096x1024        [dead after Wo gemm]
  float* x2  = (float*)(ws + 64 * MB);  // 4096x1024 fp32
  bf16* xn2  = (bf16*)(ws + 80 * MB);   // 4096x1024
  bf16* h1   = (bf16*)(ws + 88 * MB);   // 4096x4096        [written after woP consumed]
  bf16* woP  = (bf16*)(ws + 88 * MB);   // 2x 4096x1024 Wo partials (reuses h1 region)
  bf16* w2P  = (bf16*)(ws + 32 * MB);   // 4x 4096x1024 W2 partials (reuses q/k/v/att)
  bf16* WoT  = WqkvT + 3 * (size_t)NC * NC;

  transpose_all_kernel<<<12288, dim3(32, 8), 0, stream>>>(
      Wq, Wk, Wv, Wo, W1, W2, WqkvT, W1T, W2T);

  ln_cast_kernel<<<NROWS, 256, 0, stream>>>(x, ln1_g, ln1_b, xn1);

  gemm256<MODE_QKV><<<dim3(12, 16, 1), 512, 0, stream>>>(
      xn1, WqkvT, bq, bk, bv, qb, kfB, vfB, NROWS, 3 * NC, NC, NC);

  attn_kernel<<<2048, 256, 0, stream>>>(qb, kfB, vfB, att);

  gemm256<MODE_PART><<<dim3(4, 16, 2), 512, 0, stream>>>(
      att, WoT, nullptr, nullptr, nullptr, woP, nullptr, nullptr, NROWS, NC, NC, NC / 2);

  wo_ln_kernel<<<NROWS, 256, 0, stream>>>(x, bo, woP, ln2_g, ln2_b, x2, xn2);

  gemm256<MODE_GELU><<<dim3(16, 16, 1), 512, 0, stream>>>(
      xn2, W1T, b1, nullptr, nullptr, h1, nullptr, nullptr, NROWS, DFF, NC, NC);

  gemm256<MODE_PART><<<dim3(4, 16, 4), 512, 0, stream>>>(
      h1, W2T, nullptr, nullptr, nullptr, w2P, nullptr, nullptr, NROWS, NC, DFF, DFF / 4);

  w2_final_kernel<<<NROWS, 256, 0, stream>>>(x2, b2, w2P, (float*)d_out);
}

// Round 7
// 357.094 us; speedup vs baseline: 1.0065x; 1.0065x over previous
//
#include <hip/hip_runtime.h>
#include <hip/hip_bf16.h>

typedef __hip_bfloat16 bf16;
using bf16x8 = __attribute__((ext_vector_type(8))) short;
using f32x4  = __attribute__((ext_vector_type(4))) float;
using f32x16 = __attribute__((ext_vector_type(16))) float;
using u32x4  = __attribute__((ext_vector_type(4))) unsigned int;

#define TSEQ 2048
#define NH   16
#define HD   64
#define NC   1024
#define DFF  4096
#define NROWS 4096   // B*T

__device__ __forceinline__ void load_lds16(const bf16* g, bf16* l) {
  __builtin_amdgcn_global_load_lds(
      (const __attribute__((address_space(1))) unsigned int*)g,
      (__attribute__((address_space(3))) unsigned int*)l, 16, 0, 0);
}

__device__ __forceinline__ float b2f(short s) {
  unsigned int u = ((unsigned int)(unsigned short)s) << 16;
  return __builtin_bit_cast(float, u);
}

// pack two f32 -> two bf16 (RNE), single instruction; dst.lo = a, dst.hi = b
__device__ __forceinline__ unsigned cvtpk(float a, float b) {
  unsigned r;
  asm("v_cvt_pk_bf16_f32 %0, %1, %2" : "=v"(r) : "v"(a), "v"(b));
  return r;
}

// v_permlane32_swap_b32 vdst, src: vdst[32:63] <-> src[0:31]
__device__ __forceinline__ void pl32swap(unsigned &d, unsigned &s) {
  asm("v_permlane32_swap_b32 %0, %1" : "+v"(d), "+v"(s));
}

// tanh-approx GELU via hw exp; |err| < ~1e-3 (vs exact-erf reference)
__device__ __forceinline__ float gelu_f(float x) {
  float u = 0.7978845608028654f * fmaf(0.044715f * x, x * x, x);
  float e = __expf(2.0f * u);
  float t = 1.0f - 2.0f / (e + 1.0f);   // tanh(u)
  return 0.5f * x * (1.0f + t);
}

// ---------------- LayerNorm (fp32 in) -> bf16 out ----------------
__global__ __launch_bounds__(256)
void ln_cast_kernel(const float* __restrict__ x, const float* __restrict__ g,
                    const float* __restrict__ b, bf16* __restrict__ out) {
  int row = blockIdx.x, tid = threadIdx.x;
  const float4 v = ((const float4*)(x + (size_t)row * NC))[tid];
  float s  = v.x + v.y + v.z + v.w;
  float s2 = v.x*v.x + v.y*v.y + v.z*v.z + v.w*v.w;
#pragma unroll
  for (int m = 1; m < 64; m <<= 1) { s += __shfl_xor(s, m); s2 += __shfl_xor(s2, m); }
  __shared__ float rs[4], rs2[4];
  if ((tid & 63) == 0) { rs[tid >> 6] = s; rs2[tid >> 6] = s2; }
  __syncthreads();
  s  = rs[0] + rs[1] + rs[2] + rs[3];
  s2 = rs2[0] + rs2[1] + rs2[2] + rs2[3];
  float mu   = s * (1.0f / NC);
  float var  = s2 * (1.0f / NC) - mu * mu;
  float rstd = rsqrtf(var + 1e-5f);
  const float4 gv = ((const float4*)g)[tid];
  const float4 bv = ((const float4*)b)[tid];
  bf16* o = out + (size_t)row * NC + tid * 4;
  o[0] = __float2bfloat16((v.x - mu) * rstd * gv.x + bv.x);
  o[1] = __float2bfloat16((v.y - mu) * rstd * gv.y + bv.y);
  o[2] = __float2bfloat16((v.z - mu) * rstd * gv.z + bv.z);
  o[3] = __float2bfloat16((v.w - mu) * rstd * gv.w + bv.w);
}

// ---- x2 = x + bo + P0 + P1 (bf16 partials); then LN(x2) -> xn2 (fused) ----
__global__ __launch_bounds__(256)
void wo_ln_kernel(const float* __restrict__ x, const float* __restrict__ bo,
                  const bf16* __restrict__ P, const float* __restrict__ g,
                  const float* __restrict__ bln, float* __restrict__ x2,
                  bf16* __restrict__ xn2) {
  int row = blockIdx.x, tid = threadIdx.x;
  size_t base = (size_t)row * NC + tid * 4;
  const float4 xv = *(const float4*)(x + base);
  const float4 bv = ((const float4*)bo)[tid];
  short4 p0 = *(const short4*)((const short*)P + base);
  short4 p1 = *(const short4*)((const short*)P + (size_t)NROWS * NC + base);
  float v0 = xv.x + bv.x + b2f(p0.x) + b2f(p1.x);
  float v1 = xv.y + bv.y + b2f(p0.y) + b2f(p1.y);
  float v2 = xv.z + bv.z + b2f(p0.z) + b2f(p1.z);
  float v3 = xv.w + bv.w + b2f(p0.w) + b2f(p1.w);
  float4 ov = {v0, v1, v2, v3};
  *(float4*)(x2 + base) = ov;
  float s  = v0 + v1 + v2 + v3;
  float s2 = v0*v0 + v1*v1 + v2*v2 + v3*v3;
#pragma unroll
  for (int m = 1; m < 64; m <<= 1) { s += __shfl_xor(s, m); s2 += __shfl_xor(s2, m); }
  __shared__ float rs[4], rs2[4];
  if ((tid & 63) == 0) { rs[tid >> 6] = s; rs2[tid >> 6] = s2; }
  __syncthreads();
  s  = rs[0] + rs[1] + rs[2] + rs[3];
  s2 = rs2[0] + rs2[1] + rs2[2] + rs2[3];
  float mu   = s * (1.0f / NC);
  float var  = s2 * (1.0f / NC) - mu * mu;
  float rstd = rsqrtf(var + 1e-5f);
  const float4 gv = ((const float4*)g)[tid];
  const float4 lv = ((const float4*)bln)[tid];
  bf16* o = xn2 + base;
  o[0] = __float2bfloat16((v0 - mu) * rstd * gv.x + lv.x);
  o[1] = __float2bfloat16((v1 - mu) * rstd * gv.y + lv.y);
  o[2] = __float2bfloat16((v2 - mu) * rstd * gv.z + lv.z);
  o[3] = __float2bfloat16((v3 - mu) * rstd * gv.w + lv.w);
}

// ---- d_out = x2 + b2 + sum of 4 bf16 partials ----
__global__ __launch_bounds__(256)
void w2_final_kernel(const float* __restrict__ x2, const float* __restrict__ b2,
                     const bf16* __restrict__ P, float* __restrict__ out) {
  int row = blockIdx.x, tid = threadIdx.x;
  size_t base = (size_t)row * NC + tid * 4;
  const float4 xv = *(const float4*)(x2 + base);
  const float4 bv = ((const float4*)b2)[tid];
  float a0 = xv.x + bv.x, a1 = xv.y + bv.y, a2 = xv.z + bv.z, a3 = xv.w + bv.w;
#pragma unroll
  for (int z = 0; z < 4; ++z) {
    short4 p = *(const short4*)((const short*)P + (size_t)z * NROWS * NC + base);
    a0 += b2f(p.x); a1 += b2f(p.y); a2 += b2f(p.z); a3 += b2f(p.w);
  }
  float4 ov = {a0, a1, a2, a3};
  *(float4*)(out + base) = ov;
}

// ---------------- all weight transposes in one launch ----------------
__global__ __launch_bounds__(256)
void transpose_all_kernel(const float* __restrict__ Wq, const float* __restrict__ Wk,
                          const float* __restrict__ Wv, const float* __restrict__ Wo,
                          const float* __restrict__ W1, const float* __restrict__ W2,
                          bf16* __restrict__ WqkvoT, bf16* __restrict__ W1T,
                          bf16* __restrict__ W2T) {
  int bid = blockIdx.x;
  const float* W; bf16* Wt; int K, N, nx, tile;
  if (bid < 4096) {
    int z = bid >> 10; tile = bid & 1023;
    W = (z == 0) ? Wq : (z == 1) ? Wk : (z == 2) ? Wv : Wo;
    Wt = WqkvoT + (size_t)z * NC * NC; K = NC; N = NC; nx = 32;
  } else if (bid < 8192) {
    tile = bid - 4096; W = W1; Wt = W1T; K = NC; N = DFF; nx = 128;
  } else {
    tile = bid - 8192; W = W2; Wt = W2T; K = DFF; N = NC; nx = 32;
  }
  int n0 = (tile % nx) * 32, k0 = (tile / nx) * 32;
  __shared__ float t[32][33];
  int tx = threadIdx.x, ty = threadIdx.y;  // 32 x 8
#pragma unroll
  for (int i = 0; i < 4; ++i)
    t[ty + i * 8][tx] = W[(size_t)(k0 + ty + i * 8) * N + n0 + tx];
  __syncthreads();
#pragma unroll
  for (int i = 0; i < 4; ++i)
    Wt[(size_t)(n0 + ty + i * 8) * K + k0 + tx] = __float2bfloat16(t[tx][ty + i * 8]);
}

// ---------------- GEMM v3.1: 256x256 block, 8 waves, depth-3 pipeline, lane-major LDS ----
// C(MxN) = A(MxK,bf16) @ Bt(NxK,bf16)^T. BK=32, 4 rotating LDS buffers (128KB).
// LDS layout: per K-tile buffer = 16 blocks of 1KB; block (rg*2+ks) holds the
// 32-row-group rg, k-slice ks fragment with LANE-MAJOR order: lane l's 16B at
// block + l*16 (l&31 = row-in-group, l>>5 = k-half). So:
//  - global_load_lds dest linear (HW constraint); permutation folded into per-lane
//    global SOURCE address (row = w*32+(l&31), koff = (l>>5)*8);
//  - every ds_read_b128 reads block + lane*16 -> consecutive 16B per consecutive
//    lane -> ZERO bank conflicts (v3 had 8-way: lane order != slot order).
// Sync per K-tile: s_waitcnt vmcnt(8) (tiles t+1,t+2 in flight) + raw s_barrier.
#define MODE_GELU 4
#define MODE_QKV  5
#define MODE_PART 6

template <int MODE>
__global__ __launch_bounds__(512, 2)
void gemm256(const bf16* __restrict__ A, const bf16* __restrict__ Bt,
             const float* __restrict__ bias, const float* __restrict__ bias2,
             const float* __restrict__ bias3,
             void* __restrict__ outp, void* __restrict__ out2, void* __restrict__ out3,
             int M, int N, int K, int KS) {
  __shared__ bf16 lds[65536];   // A: 4 bufs x 8192 elems; B: +32768
  int tid  = threadIdx.x;
  int w    = tid >> 6;
  int lane = tid & 63;
  int l31  = lane & 31;
  int kb   = lane >> 5;          // k-half of fragment
  int wm   = w >> 2, wn = w & 3; // 2x4 wave grid; wave tile 128x64

  // block swizzle (GROUP_M = 4, col-major within group)
  int gN = gridDim.x, gM = gridDim.y;
  int pid = blockIdx.y * gN + blockIdx.x;
  int npg = 4 * gN;
  int gid = pid / npg;
  int fm  = gid * 4;
  int gsz = min(gM - fm, 4);
  int bm = (fm + (pid % gsz)) * 256;
  int bn = ((pid % npg) / gsz) * 256;
  int k_beg = blockIdx.z * KS;

  // staging: wave w stages row/col-group w; instr j = k-slice ks.
  // lane l sources row = w*32 + (l&31), k-offset = j*16 + (l>>5)*8  (lane-major)
  int srow  = w * 32 + l31;
  int skoff = kb * 8;
  const bf16* sA[2]; const bf16* sB[2];
#pragma unroll
  for (int j = 0; j < 2; ++j) {
    sA[j] = A  + (size_t)(bm + srow) * K + k_beg + j * 16 + skoff;
    sB[j] = Bt + (size_t)(bn + srow) * K + k_beg + j * 16 + skoff;
  }

  auto stage = [&](int t) {
    int b = t & 3;
    bf16* dA = &lds[b * 8192];
    bf16* dB = &lds[32768 + b * 8192];
    int koff = t * 32;
#pragma unroll
    for (int j = 0; j < 2; ++j) {
      load_lds16(sA[j] + koff, dA + (w * 2 + j) * 512);
      load_lds16(sB[j] + koff, dB + (w * 2 + j) * 512);
    }
  };

  f32x16 acc[4][2];
#pragma unroll
  for (int mi = 0; mi < 4; ++mi)
#pragma unroll
    for (int ni = 0; ni < 2; ++ni)
#pragma unroll
      for (int r = 0; r < 16; ++r) acc[mi][ni][r] = 0.f;

  int NT = KS >> 5;
  stage(0); stage(1); stage(2);   // depth-3 prologue (12 loads/wave in flight)

  for (int t = 0; t < NT; ++t) {
    // own tile-t loads retired; barrier implies the same for all waves,
    // so tile-t data is complete in LDS. Tiles t+1,t+2 stay in flight.
    if (t < NT - 2)       asm volatile("s_waitcnt vmcnt(8)" ::: "memory");
    else if (t == NT - 2) asm volatile("s_waitcnt vmcnt(4)" ::: "memory");
    else                  asm volatile("s_waitcnt vmcnt(0)" ::: "memory");
    __builtin_amdgcn_s_barrier();
    asm volatile("" ::: "memory");
    if (t + 3 < NT) stage(t + 3);   // into buf (t+3)&3 == (t-1)&3, freed by barrier

    const bf16* bufA = &lds[(t & 3) * 8192];
    const bf16* bufB = &lds[32768 + (t & 3) * 8192];
    bf16x8 af[2][4], bfr[2][2];
#pragma unroll
    for (int ks = 0; ks < 2; ++ks) {
#pragma unroll
      for (int mi = 0; mi < 4; ++mi)
        af[ks][mi] = *(const bf16x8*)&bufA[((wm * 4 + mi) * 2 + ks) * 512 + lane * 8];
#pragma unroll
      for (int ni = 0; ni < 2; ++ni)
        bfr[ks][ni] = *(const bf16x8*)&bufB[((wn * 2 + ni) * 2 + ks) * 512 + lane * 8];
    }
    __builtin_amdgcn_s_setprio(1);
#pragma unroll
    for (int ks = 0; ks < 2; ++ks)
#pragma unroll
      for (int mi = 0; mi < 4; ++mi)
#pragma unroll
        for (int ni = 0; ni < 2; ++ni)
          acc[mi][ni] = __builtin_amdgcn_mfma_f32_32x32x16_bf16(af[ks][mi], bfr[ks][ni], acc[mi][ni], 0, 0, 0);
    __builtin_amdgcn_s_setprio(0);
  }

  // ---- epilogues (C: col = l31 of B-frag, row = (reg&3)+8*(reg>>2)+4*kb) ----
  if (MODE == MODE_PART) {
    bf16* dst = (bf16*)outp + (size_t)blockIdx.z * M * N;
#pragma unroll
    for (int mi = 0; mi < 4; ++mi)
#pragma unroll
      for (int ni = 0; ni < 2; ++ni) {
        int col = bn + wn * 64 + ni * 32 + l31;
#pragma unroll
        for (int reg = 0; reg < 16; ++reg) {
          int row = bm + wm * 128 + mi * 32 + (reg & 3) + 8 * (reg >> 2) + 4 * kb;
          dst[(size_t)row * N + col] = __float2bfloat16(acc[mi][ni][reg]);
        }
      }
  } else if (MODE == MODE_GELU) {
    float bcol[2];
#pragma unroll
    for (int ni = 0; ni < 2; ++ni) bcol[ni] = bias[bn + wn * 64 + ni * 32 + l31];
#pragma unroll
    for (int mi = 0; mi < 4; ++mi)
#pragma unroll
      for (int ni = 0; ni < 2; ++ni) {
        int col = bn + wn * 64 + ni * 32 + l31;
#pragma unroll
        for (int reg = 0; reg < 16; ++reg) {
          int row = bm + wm * 128 + mi * 32 + (reg & 3) + 8 * (reg >> 2) + 4 * kb;
          ((bf16*)outp)[(size_t)row * N + col] =
              __float2bfloat16(gelu_f(acc[mi][ni][reg] + bcol[ni]));
        }
      }
  } else {  // MODE_QKV: seg block-uniform; q -> (b,h,t,d); k -> Kf frag; v -> Vf frag
    int seg = bn >> 10;
    int c1b = (bn & (NC - 1)) + wn * 64;
    const float* bp = (seg == 0) ? bias : (seg == 1) ? bias2 : bias3;
    float bcol[2]; int hh[2], dd[2];
#pragma unroll
    for (int ni = 0; ni < 2; ++ni) {
      int c1 = c1b + ni * 32 + l31;
      bcol[ni] = bp[c1]; hh[ni] = c1 >> 6; dd[ni] = c1 & (HD - 1);
    }
    if (seg == 0) {
      bf16* dst = (bf16*)outp;
#pragma unroll
      for (int mi = 0; mi < 4; ++mi)
#pragma unroll
        for (int reg = 0; reg < 16; ++reg) {
          int row = bm + wm * 128 + mi * 32 + (reg & 3) + 8 * (reg >> 2) + 4 * kb;
          int bbi = row >> 11, t = row & (TSEQ - 1);
#pragma unroll
          for (int ni = 0; ni < 2; ++ni)
            dst[((size_t)(bbi * NH + hh[ni]) * TSEQ + t) * HD + dd[ni]] =
                __float2bfloat16(acc[mi][ni][reg] + bcol[ni]);
        }
    } else if (seg == 1) {
      // Kf[bh][kt(64)][ds(4)][lane(64)][8]
      bf16* dst = (bf16*)out2;
#pragma unroll
      for (int mi = 0; mi < 4; ++mi)
#pragma unroll
        for (int reg = 0; reg < 16; ++reg) {
          int row = bm + wm * 128 + mi * 32 + (reg & 3) + 8 * (reg >> 2) + 4 * kb;
          int bbi = row >> 11, t = row & (TSEQ - 1);
          int kt = t >> 5, lk = t & 31;
#pragma unroll
          for (int ni = 0; ni < 2; ++ni) {
            int d = dd[ni];
            size_t off = ((((size_t)(bbi * NH + hh[ni]) * 64 + kt) * 4 + (d >> 4)) * 64
                          + ((d >> 3) & 1) * 32 + lk) * 8 + (d & 7);
            dst[off] = __float2bfloat16(acc[mi][ni][reg] + bcol[ni]);
          }
        }
    } else {
      // Vf[bh][kt(64)][dt(2)][ks(2)][lane(64)][8]
      bf16* dst = (bf16*)out3;
#pragma unroll
      for (int mi = 0; mi < 4; ++mi)
#pragma unroll
        for (int reg = 0; reg < 16; ++reg) {
          int row = bm + wm * 128 + mi * 32 + (reg & 3) + 8 * (reg >> 2) + 4 * kb;
          int bbi = row >> 11, t = row & (TSEQ - 1);
          int kt = t >> 5, rem = t & 31;
          int ks = rem >> 4, hf = (rem >> 3) & 1, j = rem & 7;
#pragma unroll
          for (int ni = 0; ni < 2; ++ni) {
            int d = dd[ni];
            size_t off = (((((size_t)(bbi * NH + hh[ni]) * 64 + kt) * 2 + (d >> 5)) * 2 + ks) * 64
                          + hf * 32 + (d & 31)) * 8 + j;
            dst[off] = __float2bfloat16(acc[mi][ni][reg] + bcol[ni]);
          }
        }
    }
  }
}

// ---------------- Flash attention v6: swapped-QK^T 32x32, split-K x4, frag-layout K/V ----
__global__ __launch_bounds__(256)
void attn_kernel(const bf16* __restrict__ q, const bf16* __restrict__ kf,
                 const bf16* __restrict__ vf, bf16* __restrict__ out) {
  int id  = blockIdx.x;            // 0..2047
  int xcd = id & 7;
  int t   = id >> 3;               // per-XCD arrival index 0..255
  int bh  = xcd * 4 + (t & 3);
  int u   = t >> 2;                // 0..63
  int qt  = (u < 32) ? (2 * u) : (63 - 2 * (u - 32));
  int b = bh >> 4, h = bh & 15;

  int tid  = threadIdx.x;
  int w    = tid >> 6;             // split-K wave 0..3
  int lane = tid & 63;
  int l31  = lane & 31;
  int hh   = lane >> 5;            // 0/1
  int h8   = hh * 8;
  int base4 = hh * 4;

  const bf16* qp  = q  + (size_t)(b * NH + h) * TSEQ * HD;
  const bf16* kfb = kf + (size_t)bh * (64 * 4 * 64 * 8);   // 256KB per (b,h)
  const bf16* vfb = vf + (size_t)bh * (64 * 2 * 2 * 64 * 8);

  int q0 = qt * 32;

  // Q fragments (B-operand): lane holds Q[q0+l31][ds*16 + h8 .. +7]
  bf16x8 qf[4];
#pragma unroll
  for (int ds = 0; ds < 4; ++ds)
    qf[ds] = *(const bf16x8*)(qp + (size_t)(q0 + l31) * HD + ds * 16 + h8);

  f32x16 o0, o1;
#pragma unroll
  for (int r = 0; r < 16; ++r) { o0[r] = 0.f; o1[r] = 0.f; }
  float lacc = 0.f;

  bf16x8 a0, a1, a2, a3;           // K fragments (A-operand), pipelined

  auto step = [&](int kt, bool dg) {
    const bf16* vs = vfb + (size_t)kt * 2048 + lane * 8;
    bf16x8 v00 = *(const bf16x8*)(vs);            // dt0 ks0
    bf16x8 v01 = *(const bf16x8*)(vs + 512);      // dt0 ks1
    bf16x8 v10 = *(const bf16x8*)(vs + 1024);     // dt1 ks0
    bf16x8 v11 = *(const bf16x8*)(vs + 1536);     // dt1 ks1
    bf16x8 n0, n1, n2, n3;
    bool pf = !dg && (kt + 4 <= qt);
    if (pf) {
      const bf16* kn = kfb + (size_t)(kt + 4) * 2048 + lane * 8;
      n0 = *(const bf16x8*)(kn);
      n1 = *(const bf16x8*)(kn + 512);
      n2 = *(const bf16x8*)(kn + 1024);
      n3 = *(const bf16x8*)(kn + 1536);
    }

    f32x16 c;
#pragma unroll
    for (int r = 0; r < 16; ++r) c[r] = 0.f;
    c = __builtin_amdgcn_mfma_f32_32x32x16_bf16(a0, qf[0], c, 0, 0, 0);
    c = __builtin_amdgcn_mfma_f32_32x32x16_bf16(a1, qf[1], c, 0, 0, 0);
    c = __builtin_amdgcn_mfma_f32_32x32x16_bf16(a2, qf[2], c, 0, 0, 0);
    c = __builtin_amdgcn_mfma_f32_32x32x16_bf16(a3, qf[3], c, 0, 0, 0);

    float p[16];
    float ls = 0.f;
#pragma unroll
    for (int r = 0; r < 16; ++r) {
      float pv = exp2f(fmaf(c[r], 0.18033688011112042f, -11.541560327111707f));
      if (dg) {
        int krr = (r & 3) + 8 * (r >> 2) + base4;
        pv = (krr <= l31) ? pv : 0.f;
      }
      p[r] = pv;
      ls += pv;
    }
    lacc += ls;

    unsigned A0 = cvtpk(p[0],  p[1]),  C0 = cvtpk(p[4],  p[5]);
    unsigned B0 = cvtpk(p[2],  p[3]),  D0 = cvtpk(p[6],  p[7]);
    pl32swap(A0, C0); pl32swap(B0, D0);
    unsigned A1 = cvtpk(p[8],  p[9]),  C1 = cvtpk(p[12], p[13]);
    unsigned B1 = cvtpk(p[10], p[11]), D1 = cvtpk(p[14], p[15]);
    pl32swap(A1, C1); pl32swap(B1, D1);
    u32x4 w0v = {A0, B0, C0, D0};
    u32x4 w1v = {A1, B1, C1, D1};
    bf16x8 pa0 = __builtin_bit_cast(bf16x8, w0v);
    bf16x8 pa1 = __builtin_bit_cast(bf16x8, w1v);

    o0 = __builtin_amdgcn_mfma_f32_32x32x16_bf16(pa0, v00, o0, 0, 0, 0);
    o0 = __builtin_amdgcn_mfma_f32_32x32x16_bf16(pa1, v01, o0, 0, 0, 0);
    o1 = __builtin_amdgcn_mfma_f32_32x32x16_bf16(pa0, v10, o1, 0, 0, 0);
    o1 = __builtin_amdgcn_mfma_f32_32x32x16_bf16(pa1, v11, o1, 0, 0, 0);

    if (pf) { a0 = n0; a1 = n1; a2 = n2; a3 = n3; }
  };

  if (w <= qt) {
    const bf16* ka = kfb + (size_t)w * 2048 + lane * 8;
    a0 = *(const bf16x8*)(ka);
    a1 = *(const bf16x8*)(ka + 512);
    a2 = *(const bf16x8*)(ka + 1024);
    a3 = *(const bf16x8*)(ka + 1536);
    int diag = (w == (qt & 3)) ? 1 : 0;   // diag implies w <= qt
    int T = ((qt - w) >> 2) + 1 - diag;   // non-diag step count
    int kt = w;
    for (int i = 0; i < T; ++i, kt += 4) step(kt, false);
    if (diag) step(qt, true);
  }

  // ---- cross-wave combine: 2-round LDS tree (33-float stride: conflict-free) ----
  __shared__ float red[2][64][33];
  auto dump = [&](int slot) {
    float* d = &red[slot][lane][0];
#pragma unroll
    for (int r = 0; r < 16; ++r) { d[r] = o0[r]; d[16 + r] = o1[r]; }
    d[32] = lacc;
  };
  auto gather = [&](int slot) {
    const float* s = &red[slot][lane][0];
#pragma unroll
    for (int r = 0; r < 16; ++r) { o0[r] += s[r]; o1[r] += s[16 + r]; }
    lacc += s[32];
  };
  if (w >= 2) dump(w - 2);
  __syncthreads();
  if (w < 2) gather(w);
  __syncthreads();
  if (w == 1) dump(0);
  __syncthreads();
  if (w == 0) {
    gather(0);
    float ltot = lacc + __shfl_xor(lacc, 32);
    float linv = 1.0f / ltot;
#pragma unroll
    for (int r = 0; r < 16; ++r) {
      int qoff = (r & 3) + 8 * (r >> 2) + base4;
      float sc = __shfl(linv, qoff);
      size_t ob = ((size_t)(b * TSEQ + q0 + qoff)) * NC + h * HD + l31;
      out[ob]      = __float2bfloat16(o0[r] * sc);
      out[ob + 32] = __float2bfloat16(o1[r] * sc);
    }
  }
}

extern "C" void kernel_launch(void* const* d_in, const int* in_sizes, int n_in,
                              void* d_out, int out_size, void* d_ws, size_t ws_size,
                              hipStream_t stream) {
  const float* x     = (const float*)d_in[0];
  const float* ln1_g = (const float*)d_in[1];
  const float* ln1_b = (const float*)d_in[2];
  const float* Wq    = (const float*)d_in[3];
  const float* bq    = (const float*)d_in[4];
  const float* Wk    = (const float*)d_in[5];
  const float* bk    = (const float*)d_in[6];
  const float* Wv    = (const float*)d_in[7];
  const float* bv    = (const float*)d_in[8];
  const float* Wo    = (const float*)d_in[9];
  const float* bo    = (const float*)d_in[10];
  const float* ln2_g = (const float*)d_in[11];
  const float* ln2_b = (const float*)d_in[12];
  const float* W1    = (const float*)d_in[13];
  const float* b1    = (const float*)d_in[14];
  const float* W2    = (const float*)d_in[15];
  const float* b2    = (const float*)d_in[16];

  char* ws = (char*)d_ws;
  const size_t MB = 1u << 20;
  bf16* WqkvT = (bf16*)(ws + 0 * MB);   // 4x1024x1024 (q|k|v|o)
  bf16* W1T  = (bf16*)(ws + 8 * MB);    // 4096x1024
  bf16* W2T  = (bf16*)(ws + 16 * MB);   // 1024x4096
  bf16* xn1  = (bf16*)(ws + 24 * MB);   // 4096x1024
  bf16* qb   = (bf16*)(ws + 32 * MB);   // (b,h,t,d)        [dead after attn]
  bf16* kfB  = (bf16*)(ws + 40 * MB);   // K fragment layout [dead after attn]
  bf16* vfB  = (bf16*)(ws + 48 * MB);   // V fragment layout [dead after attn]
  bf16* att  = (bf16*)(ws + 56 * MB);   // 4096x1024        [dead after Wo gemm]
  float* x2  = (float*)(ws + 64 * MB);  // 4096x1024 fp32
  bf16* xn2  = (bf16*)(ws + 80 * MB);   // 4096x1024
  bf16* h1   = (bf16*)(ws + 88 * MB);   // 4096x4096        [written after woP consumed]
  bf16* woP  = (bf16*)(ws + 88 * MB);   // 2x 4096x1024 Wo partials (reuses h1 region)
  bf16* w2P  = (bf16*)(ws + 32 * MB);   // 4x 4096x1024 W2 partials (reuses q/k/v/att)
  bf16* WoT  = WqkvT + 3 * (size_t)NC * NC;

  transpose_all_kernel<<<12288, dim3(32, 8), 0, stream>>>(
      Wq, Wk, Wv, Wo, W1, W2, WqkvT, W1T, W2T);

  ln_cast_kernel<<<NROWS, 256, 0, stream>>>(x, ln1_g, ln1_b, xn1);

  gemm256<MODE_QKV><<<dim3(12, 16, 1), 512, 0, stream>>>(
      xn1, WqkvT, bq, bk, bv, qb, kfB, vfB, NROWS, 3 * NC, NC, NC);

  attn_kernel<<<2048, 256, 0, stream>>>(qb, kfB, vfB, att);

  gemm256<MODE_PART><<<dim3(4, 16, 2), 512, 0, stream>>>(
      att, WoT, nullptr, nullptr, nullptr, woP, nullptr, nullptr, NROWS, NC, NC, NC / 2);

  wo_ln_kernel<<<NROWS, 256, 0, stream>>>(x, bo, woP, ln2_g, ln2_b, x2, xn2);

  gemm256<MODE_GELU><<<dim3(16, 16, 1), 512, 0, stream>>>(
      xn2, W1T, b1, nullptr, nullptr, h1, nullptr, nullptr, NROWS, DFF, NC, NC);

  gemm256<MODE_PART><<<dim3(4, 16, 4), 512, 0, stream>>>(
      h1, W2T, nullptr, nullptr, nullptr, w2P, nullptr, nullptr, NROWS, NC, DFF, DFF / 4);

  w2_final_kernel<<<NROWS, 256, 0, stream>>>(x2, b2, w2P, (float*)d_out);
}

// Round 9
// 346.355 us; speedup vs baseline: 1.0377x; 1.0310x over previous
//
#include <hip/hip_runtime.h>
#include <hip/hip_bf16.h>

typedef __hip_bfloat16 bf16;
using bf16x8 = __attribute__((ext_vector_type(8))) short;
using f32x4  = __attribute__((ext_vector_type(4))) float;
using f32x16 = __attribute__((ext_vector_type(16))) float;
using u32x4  = __attribute__((ext_vector_type(4))) unsigned int;

#define TSEQ 2048
#define NH   16
#define HD   64
#define NC   1024
#define DFF  4096
#define NROWS 4096   // B*T

__device__ __forceinline__ void load_lds16(const bf16* g, bf16* l) {
  __builtin_amdgcn_global_load_lds(
      (const __attribute__((address_space(1))) unsigned int*)g,
      (__attribute__((address_space(3))) unsigned int*)l, 16, 0, 0);
}

__device__ __forceinline__ float b2f(short s) {
  unsigned int u = ((unsigned int)(unsigned short)s) << 16;
  return __builtin_bit_cast(float, u);
}

// pack two f32 -> two bf16 (RNE), single instruction; dst.lo = a, dst.hi = b
__device__ __forceinline__ unsigned cvtpk(float a, float b) {
  unsigned r;
  asm("v_cvt_pk_bf16_f32 %0, %1, %2" : "=v"(r) : "v"(a), "v"(b));
  return r;
}

// v_permlane32_swap_b32 vdst, src: vdst[32:63] <-> src[0:31]
__device__ __forceinline__ void pl32swap(unsigned &d, unsigned &s) {
  asm("v_permlane32_swap_b32 %0, %1" : "+v"(d), "+v"(s));
}

// tanh-approx GELU via hw exp; |err| < ~1e-3 (vs exact-erf reference)
__device__ __forceinline__ float gelu_f(float x) {
  float u = 0.7978845608028654f * fmaf(0.044715f * x, x * x, x);
  float e = __expf(2.0f * u);
  float t = 1.0f - 2.0f / (e + 1.0f);   // tanh(u)
  return 0.5f * x * (1.0f + t);
}

// ---------------- LayerNorm (fp32 in) -> bf16 out ----------------
__global__ __launch_bounds__(256)
void ln_cast_kernel(const float* __restrict__ x, const float* __restrict__ g,
                    const float* __restrict__ b, bf16* __restrict__ out) {
  int row = blockIdx.x, tid = threadIdx.x;
  const float4 v = ((const float4*)(x + (size_t)row * NC))[tid];
  float s  = v.x + v.y + v.z + v.w;
  float s2 = v.x*v.x + v.y*v.y + v.z*v.z + v.w*v.w;
#pragma unroll
  for (int m = 1; m < 64; m <<= 1) { s += __shfl_xor(s, m); s2 += __shfl_xor(s2, m); }
  __shared__ float rs[4], rs2[4];
  if ((tid & 63) == 0) { rs[tid >> 6] = s; rs2[tid >> 6] = s2; }
  __syncthreads();
  s  = rs[0] + rs[1] + rs[2] + rs[3];
  s2 = rs2[0] + rs2[1] + rs2[2] + rs2[3];
  float mu   = s * (1.0f / NC);
  float var  = s2 * (1.0f / NC) - mu * mu;
  float rstd = rsqrtf(var + 1e-5f);
  const float4 gv = ((const float4*)g)[tid];
  const float4 bv = ((const float4*)b)[tid];
  bf16* o = out + (size_t)row * NC + tid * 4;
  o[0] = __float2bfloat16((v.x - mu) * rstd * gv.x + bv.x);
  o[1] = __float2bfloat16((v.y - mu) * rstd * gv.y + bv.y);
  o[2] = __float2bfloat16((v.z - mu) * rstd * gv.z + bv.z);
  o[3] = __float2bfloat16((v.w - mu) * rstd * gv.w + bv.w);
}

// ---- x2 = x + bo + P0 + P1 (bf16 partials); then LN(x2) -> xn2 (fused) ----
__global__ __launch_bounds__(256)
void wo_ln_kernel(const float* __restrict__ x, const float* __restrict__ bo,
                  const bf16* __restrict__ P, const float* __restrict__ g,
                  const float* __restrict__ bln, float* __restrict__ x2,
                  bf16* __restrict__ xn2) {
  int row = blockIdx.x, tid = threadIdx.x;
  size_t base = (size_t)row * NC + tid * 4;
  const float4 xv = *(const float4*)(x + base);
  const float4 bv = ((const float4*)bo)[tid];
  short4 p0 = *(const short4*)((const short*)P + base);
  short4 p1 = *(const short4*)((const short*)P + (size_t)NROWS * NC + base);
  float v0 = xv.x + bv.x + b2f(p0.x) + b2f(p1.x);
  float v1 = xv.y + bv.y + b2f(p0.y) + b2f(p1.y);
  float v2 = xv.z + bv.z + b2f(p0.z) + b2f(p1.z);
  float v3 = xv.w + bv.w + b2f(p0.w) + b2f(p1.w);
  float4 ov = {v0, v1, v2, v3};
  *(float4*)(x2 + base) = ov;
  float s  = v0 + v1 + v2 + v3;
  float s2 = v0*v0 + v1*v1 + v2*v2 + v3*v3;
#pragma unroll
  for (int m = 1; m < 64; m <<= 1) { s += __shfl_xor(s, m); s2 += __shfl_xor(s2, m); }
  __shared__ float rs[4], rs2[4];
  if ((tid & 63) == 0) { rs[tid >> 6] = s; rs2[tid >> 6] = s2; }
  __syncthreads();
  s  = rs[0] + rs[1] + rs[2] + rs[3];
  s2 = rs2[0] + rs2[1] + rs2[2] + rs2[3];
  float mu   = s * (1.0f / NC);
  float var  = s2 * (1.0f / NC) - mu * mu;
  float rstd = rsqrtf(var + 1e-5f);
  const float4 gv = ((const float4*)g)[tid];
  const float4 lv = ((const float4*)bln)[tid];
  bf16* o = xn2 + base;
  o[0] = __float2bfloat16((v0 - mu) * rstd * gv.x + lv.x);
  o[1] = __float2bfloat16((v1 - mu) * rstd * gv.y + lv.y);
  o[2] = __float2bfloat16((v2 - mu) * rstd * gv.z + lv.z);
  o[3] = __float2bfloat16((v3 - mu) * rstd * gv.w + lv.w);
}

// ---- d_out = x2 + b2 + sum of 4 bf16 partials ----
__global__ __launch_bounds__(256)
void w2_final_kernel(const float* __restrict__ x2, const float* __restrict__ b2,
                     const bf16* __restrict__ P, float* __restrict__ out) {
  int row = blockIdx.x, tid = threadIdx.x;
  size_t base = (size_t)row * NC + tid * 4;
  const float4 xv = *(const float4*)(x2 + base);
  const float4 bv = ((const float4*)b2)[tid];
  float a0 = xv.x + bv.x, a1 = xv.y + bv.y, a2 = xv.z + bv.z, a3 = xv.w + bv.w;
#pragma unroll
  for (int z = 0; z < 4; ++z) {
    short4 p = *(const short4*)((const short*)P + (size_t)z * NROWS * NC + base);
    a0 += b2f(p.x); a1 += b2f(p.y); a2 += b2f(p.z); a3 += b2f(p.w);
  }
  float4 ov = {a0, a1, a2, a3};
  *(float4*)(out + base) = ov;
}

// ---------------- all weight transposes in one launch ----------------
__global__ __launch_bounds__(256)
void transpose_all_kernel(const float* __restrict__ Wq, const float* __restrict__ Wk,
                          const float* __restrict__ Wv, const float* __restrict__ Wo,
                          const float* __restrict__ W1, const float* __restrict__ W2,
                          bf16* __restrict__ WqkvoT, bf16* __restrict__ W1T,
                          bf16* __restrict__ W2T) {
  int bid = blockIdx.x;
  const float* W; bf16* Wt; int K, N, nx, tile;
  if (bid < 4096) {
    int z = bid >> 10; tile = bid & 1023;
    W = (z == 0) ? Wq : (z == 1) ? Wk : (z == 2) ? Wv : Wo;
    Wt = WqkvoT + (size_t)z * NC * NC; K = NC; N = NC; nx = 32;
  } else if (bid < 8192) {
    tile = bid - 4096; W = W1; Wt = W1T; K = NC; N = DFF; nx = 128;
  } else {
    tile = bid - 8192; W = W2; Wt = W2T; K = DFF; N = NC; nx = 32;
  }
  int n0 = (tile % nx) * 32, k0 = (tile / nx) * 32;
  __shared__ float t[32][33];
  int tx = threadIdx.x, ty = threadIdx.y;  // 32 x 8
#pragma unroll
  for (int i = 0; i < 4; ++i)
    t[ty + i * 8][tx] = W[(size_t)(k0 + ty + i * 8) * N + n0 + tx];
  __syncthreads();
#pragma unroll
  for (int i = 0; i < 4; ++i)
    Wt[(size_t)(n0 + ty + i * 8) * K + k0 + tx] = __float2bfloat16(t[tx][ty + i * 8]);
}

// ---------------- GEMM v4: 256x256, 8 waves, depth-3 pipeline, 2-phase interleave ----
// C(MxN) = A(MxK,bf16) @ Bt(NxK,bf16)^T. BK=32, 4 rotating LDS buffers (128KB),
// lane-major fragment blocks (conflict-free ds_read_b128, v3.1).
// K-loop is the T3 fine-interleaved schedule (m201/m218 class): each BK=32 tile =
// 2 phases of {6 ds_read -> issue 2 global_load_lds -> s_barrier -> lgkmcnt(0)+
// sched_barrier(0) -> setprio(1) 8 MFMA setprio(0) -> s_barrier}; counted
// s_waitcnt vmcnt(8) ONCE per tile at loop top (t+1..t+3 stay in flight, never
// drained mid-loop).
#define MODE_GELU 4
#define MODE_QKV  5
#define MODE_PART 6

template <int MODE>
__global__ __launch_bounds__(512, 2)
void gemm256(const bf16* __restrict__ A, const bf16* __restrict__ Bt,
             const float* __restrict__ bias, const float* __restrict__ bias2,
             const float* __restrict__ bias3,
             void* __restrict__ outp, void* __restrict__ out2, void* __restrict__ out3,
             int M, int N, int K, int KS) {
  __shared__ bf16 lds[65536];   // A: 4 bufs x 8192 elems; B: +32768
  int tid  = threadIdx.x;
  int w    = tid >> 6;
  int lane = tid & 63;
  int l31  = lane & 31;
  int kb   = lane >> 5;          // k-half of fragment
  int wm   = w >> 2, wn = w & 3; // 2x4 wave grid; wave tile 128x64

  // block swizzle (GROUP_M = 4, col-major within group)
  int gN = gridDim.x, gM = gridDim.y;
  int pid = blockIdx.y * gN + blockIdx.x;
  int npg = 4 * gN;
  int gid = pid / npg;
  int fm  = gid * 4;
  int gsz = min(gM - fm, 4);
  int bm = (fm + (pid % gsz)) * 256;
  int bn = ((pid % npg) / gsz) * 256;
  int k_beg = blockIdx.z * KS;

  // staging: wave w stages row/col-group w; instr j = k-slice ks.
  // lane l sources row = w*32 + (l&31), k-offset = j*16 + (l>>5)*8  (lane-major)
  int srow  = w * 32 + l31;
  int skoff = kb * 8;
  const bf16* sA[2]; const bf16* sB[2];
#pragma unroll
  for (int j = 0; j < 2; ++j) {
    sA[j] = A  + (size_t)(bm + srow) * K + k_beg + j * 16 + skoff;
    sB[j] = Bt + (size_t)(bn + srow) * K + k_beg + j * 16 + skoff;
  }

  auto stageA = [&](int t) {
    bf16* dA = &lds[(t & 3) * 8192];
    int koff = t * 32;
    load_lds16(sA[0] + koff, dA + (w * 2 + 0) * 512);
    load_lds16(sA[1] + koff, dA + (w * 2 + 1) * 512);
  };
  auto stageB = [&](int t) {
    bf16* dB = &lds[32768 + (t & 3) * 8192];
    int koff = t * 32;
    load_lds16(sB[0] + koff, dB + (w * 2 + 0) * 512);
    load_lds16(sB[1] + koff, dB + (w * 2 + 1) * 512);
  };

  f32x16 acc[4][2];
#pragma unroll
  for (int mi = 0; mi < 4; ++mi)
#pragma unroll
    for (int ni = 0; ni < 2; ++ni)
#pragma unroll
      for (int r = 0; r < 16; ++r) acc[mi][ni][r] = 0.f;

  int NT = KS >> 5;
  stageA(0); stageB(0); stageA(1); stageB(1); stageA(2); stageB(2);  // depth-3

  for (int t = 0; t < NT; ++t) {
    // counted wait: stage(t) landed; stages t+1..t+3 remain in flight.
    if (t < NT - 2)       asm volatile("s_waitcnt vmcnt(8)" ::: "memory");
    else if (t == NT - 2) asm volatile("s_waitcnt vmcnt(4)" ::: "memory");
    else                  asm volatile("s_waitcnt vmcnt(0)" ::: "memory");
    __builtin_amdgcn_s_barrier();

    const bf16* bufA = &lds[(t & 3) * 8192];
    const bf16* bufB = &lds[32768 + (t & 3) * 8192];

    // ---- phase 0 (ks = 0) ----
    bf16x8 af0[4], bf0[2];
#pragma unroll
    for (int mi = 0; mi < 4; ++mi)
      af0[mi] = *(const bf16x8*)&bufA[((wm * 4 + mi) * 2 + 0) * 512 + lane * 8];
#pragma unroll
    for (int ni = 0; ni < 2; ++ni)
      bf0[ni] = *(const bf16x8*)&bufB[((wn * 2 + ni) * 2 + 0) * 512 + lane * 8];
    if (t + 3 < NT) stageA(t + 3);
    __builtin_amdgcn_s_barrier();
    asm volatile("s_waitcnt lgkmcnt(0)" ::: "memory");
    __builtin_amdgcn_sched_barrier(0);
    __builtin_amdgcn_s_setprio(1);
#pragma unroll
    for (int mi = 0; mi < 4; ++mi)
#pragma unroll
      for (int ni = 0; ni < 2; ++ni)
        acc[mi][ni] = __builtin_amdgcn_mfma_f32_32x32x16_bf16(af0[mi], bf0[ni], acc[mi][ni], 0, 0, 0);
    __builtin_amdgcn_s_setprio(0);
    __builtin_amdgcn_s_barrier();

    // ---- phase 1 (ks = 1) ----
    bf16x8 af1[4], bf1[2];
#pragma unroll
    for (int mi = 0; mi < 4; ++mi)
      af1[mi] = *(const bf16x8*)&bufA[((wm * 4 + mi) * 2 + 1) * 512 + lane * 8];
#pragma unroll
    for (int ni = 0; ni < 2; ++ni)
      bf1[ni] = *(const bf16x8*)&bufB[((wn * 2 + ni) * 2 + 1) * 512 + lane * 8];
    if (t + 3 < NT) stageB(t + 3);
    __builtin_amdgcn_s_barrier();
    asm volatile("s_waitcnt lgkmcnt(0)" ::: "memory");
    __builtin_amdgcn_sched_barrier(0);
    __builtin_amdgcn_s_setprio(1);
#pragma unroll
    for (int mi = 0; mi < 4; ++mi)
#pragma unroll
      for (int ni = 0; ni < 2; ++ni)
        acc[mi][ni] = __builtin_amdgcn_mfma_f32_32x32x16_bf16(af1[mi], bf1[ni], acc[mi][ni], 0, 0, 0);
    __builtin_amdgcn_s_setprio(0);
    // loop-top vmcnt + barrier closes the iteration
  }

  // ---- epilogues (C: col = l31 of B-frag, row = (reg&3)+8*(reg>>2)+4*kb) ----
  if (MODE == MODE_PART) {
    bf16* dst = (bf16*)outp + (size_t)blockIdx.z * M * N;
#pragma unroll
    for (int mi = 0; mi < 4; ++mi)
#pragma unroll
      for (int ni = 0; ni < 2; ++ni) {
        int col = bn + wn * 64 + ni * 32 + l31;
#pragma unroll
        for (int reg = 0; reg < 16; ++reg) {
          int row = bm + wm * 128 + mi * 32 + (reg & 3) + 8 * (reg >> 2) + 4 * kb;
          dst[(size_t)row * N + col] = __float2bfloat16(acc[mi][ni][reg]);
        }
      }
  } else if (MODE == MODE_GELU) {
    float bcol[2];
#pragma unroll
    for (int ni = 0; ni < 2; ++ni) bcol[ni] = bias[bn + wn * 64 + ni * 32 + l31];
#pragma unroll
    for (int mi = 0; mi < 4; ++mi)
#pragma unroll
      for (int ni = 0; ni < 2; ++ni) {
        int col = bn + wn * 64 + ni * 32 + l31;
#pragma unroll
        for (int reg = 0; reg < 16; ++reg) {
          int row = bm + wm * 128 + mi * 32 + (reg & 3) + 8 * (reg >> 2) + 4 * kb;
          ((bf16*)outp)[(size_t)row * N + col] =
              __float2bfloat16(gelu_f(acc[mi][ni][reg] + bcol[ni]));
        }
      }
  } else {  // MODE_QKV: seg block-uniform; q -> (b,h,t,d); k -> Kf frag; v -> Vf frag
    int seg = bn >> 10;
    int c1b = (bn & (NC - 1)) + wn * 64;
    const float* bp = (seg == 0) ? bias : (seg == 1) ? bias2 : bias3;
    float bcol[2]; int hh[2], dd[2];
#pragma unroll
    for (int ni = 0; ni < 2; ++ni) {
      int c1 = c1b + ni * 32 + l31;
      bcol[ni] = bp[c1]; hh[ni] = c1 >> 6; dd[ni] = c1 & (HD - 1);
    }
    if (seg == 0) {
      bf16* dst = (bf16*)outp;
#pragma unroll
      for (int mi = 0; mi < 4; ++mi)
#pragma unroll
        for (int reg = 0; reg < 16; ++reg) {
          int row = bm + wm * 128 + mi * 32 + (reg & 3) + 8 * (reg >> 2) + 4 * kb;
          int bbi = row >> 11, t = row & (TSEQ - 1);
#pragma unroll
          for (int ni = 0; ni < 2; ++ni)
            dst[((size_t)(bbi * NH + hh[ni]) * TSEQ + t) * HD + dd[ni]] =
                __float2bfloat16(acc[mi][ni][reg] + bcol[ni]);
        }
    } else if (seg == 1) {
      // Kf[bh][kt(64)][ds(4)][lane(64)][8]
      bf16* dst = (bf16*)out2;
#pragma unroll
      for (int mi = 0; mi < 4; ++mi)
#pragma unroll
        for (int reg = 0; reg < 16; ++reg) {
          int row = bm + wm * 128 + mi * 32 + (reg & 3) + 8 * (reg >> 2) + 4 * kb;
          int bbi = row >> 11, t = row & (TSEQ - 1);
          int kt = t >> 5, lk = t & 31;
#pragma unroll
          for (int ni = 0; ni < 2; ++ni) {
            int d = dd[ni];
            size_t off = ((((size_t)(bbi * NH + hh[ni]) * 64 + kt) * 4 + (d >> 4)) * 64
                          + ((d >> 3) & 1) * 32 + lk) * 8 + (d & 7);
            dst[off] = __float2bfloat16(acc[mi][ni][reg] + bcol[ni]);
          }
        }
    } else {
      // Vf[bh][kt(64)][dt(2)][ks(2)][lane(64)][8]
      bf16* dst = (bf16*)out3;
#pragma unroll
      for (int mi = 0; mi < 4; ++mi)
#pragma unroll
        for (int reg = 0; reg < 16; ++reg) {
          int row = bm + wm * 128 + mi * 32 + (reg & 3) + 8 * (reg >> 2) + 4 * kb;
          int bbi = row >> 11, t = row & (TSEQ - 1);
          int kt = t >> 5, rem = t & 31;
          int ks = rem >> 4, hf = (rem >> 3) & 1, j = rem & 7;
#pragma unroll
          for (int ni = 0; ni < 2; ++ni) {
            int d = dd[ni];
            size_t off = (((((size_t)(bbi * NH + hh[ni]) * 64 + kt) * 2 + (d >> 5)) * 2 + ks) * 64
                          + hf * 32 + (d & 31)) * 8 + j;
            dst[off] = __float2bfloat16(acc[mi][ni][reg] + bcol[ni]);
          }
        }
    }
  }
}

// ---------------- Flash attention v6: swapped-QK^T 32x32, split-K x4, frag-layout K/V ----
__global__ __launch_bounds__(256)
void attn_kernel(const bf16* __restrict__ q, const bf16* __restrict__ kf,
                 const bf16* __restrict__ vf, bf16* __restrict__ out) {
  int id  = blockIdx.x;            // 0..2047
  int xcd = id & 7;
  int t   = id >> 3;               // per-XCD arrival index 0..255
  int bh  = xcd * 4 + (t & 3);
  int u   = t >> 2;                // 0..63
  int qt  = (u < 32) ? (2 * u) : (63 - 2 * (u - 32));
  int b = bh >> 4, h = bh & 15;

  int tid  = threadIdx.x;
  int w    = tid >> 6;             // split-K wave 0..3
  int lane = tid & 63;
  int l31  = lane & 31;
  int hh   = lane >> 5;            // 0/1
  int h8   = hh * 8;
  int base4 = hh * 4;

  const bf16* qp  = q  + (size_t)(b * NH + h) * TSEQ * HD;
  const bf16* kfb = kf + (size_t)bh * (64 * 4 * 64 * 8);   // 256KB per (b,h)
  const bf16* vfb = vf + (size_t)bh * (64 * 2 * 2 * 64 * 8);

  int q0 = qt * 32;

  // Q fragments (B-operand): lane holds Q[q0+l31][ds*16 + h8 .. +7]
  bf16x8 qf[4];
#pragma unroll
  for (int ds = 0; ds < 4; ++ds)
    qf[ds] = *(const bf16x8*)(qp + (size_t)(q0 + l31) * HD + ds * 16 + h8);

  f32x16 o0, o1;
#pragma unroll
  for (int r = 0; r < 16; ++r) { o0[r] = 0.f; o1[r] = 0.f; }
  float lacc = 0.f;

  bf16x8 a0, a1, a2, a3;           // K fragments (A-operand), pipelined

  auto step = [&](int kt, bool dg) {
    const bf16* vs = vfb + (size_t)kt * 2048 + lane * 8;
    bf16x8 v00 = *(const bf16x8*)(vs);            // dt0 ks0
    bf16x8 v01 = *(const bf16x8*)(vs + 512);      // dt0 ks1
    bf16x8 v10 = *(const bf16x8*)(vs + 1024);     // dt1 ks0
    bf16x8 v11 = *(const bf16x8*)(vs + 1536);     // dt1 ks1
    bf16x8 n0, n1, n2, n3;
    bool pf = !dg && (kt + 4 <= qt);
    if (pf) {
      const bf16* kn = kfb + (size_t)(kt + 4) * 2048 + lane * 8;
      n0 = *(const bf16x8*)(kn);
      n1 = *(const bf16x8*)(kn + 512);
      n2 = *(const bf16x8*)(kn + 1024);
      n3 = *(const bf16x8*)(kn + 1536);
    }

    f32x16 c;
#pragma unroll
    for (int r = 0; r < 16; ++r) c[r] = 0.f;
    c = __builtin_amdgcn_mfma_f32_32x32x16_bf16(a0, qf[0], c, 0, 0, 0);
    c = __builtin_amdgcn_mfma_f32_32x32x16_bf16(a1, qf[1], c, 0, 0, 0);
    c = __builtin_amdgcn_mfma_f32_32x32x16_bf16(a2, qf[2], c, 0, 0, 0);
    c = __builtin_amdgcn_mfma_f32_32x32x16_bf16(a3, qf[3], c, 0, 0, 0);

    float p[16];
    float ls = 0.f;
#pragma unroll
    for (int r = 0; r < 16; ++r) {
      float pv = exp2f(fmaf(c[r], 0.18033688011112042f, -11.541560327111707f));
      if (dg) {
        int krr = (r & 3) + 8 * (r >> 2) + base4;
        pv = (krr <= l31) ? pv : 0.f;
      }
      p[r] = pv;
      ls += pv;
    }
    lacc += ls;

    unsigned A0 = cvtpk(p[0],  p[1]),  C0 = cvtpk(p[4],  p[5]);
    unsigned B0 = cvtpk(p[2],  p[3]),  D0 = cvtpk(p[6],  p[7]);
    pl32swap(A0, C0); pl32swap(B0, D0);
    unsigned A1 = cvtpk(p[8],  p[9]),  C1 = cvtpk(p[12], p[13]);
    unsigned B1 = cvtpk(p[10], p[11]), D1 = cvtpk(p[14], p[15]);
    pl32swap(A1, C1); pl32swap(B1, D1);
    u32x4 w0v = {A0, B0, C0, D0};
    u32x4 w1v = {A1, B1, C1, D1};
    bf16x8 pa0 = __builtin_bit_cast(bf16x8, w0v);
    bf16x8 pa1 = __builtin_bit_cast(bf16x8, w1v);

    o0 = __builtin_amdgcn_mfma_f32_32x32x16_bf16(pa0, v00, o0, 0, 0, 0);
    o0 = __builtin_amdgcn_mfma_f32_32x32x16_bf16(pa1, v01, o0, 0, 0, 0);
    o1 = __builtin_amdgcn_mfma_f32_32x32x16_bf16(pa0, v10, o1, 0, 0, 0);
    o1 = __builtin_amdgcn_mfma_f32_32x32x16_bf16(pa1, v11, o1, 0, 0, 0);

    if (pf) { a0 = n0; a1 = n1; a2 = n2; a3 = n3; }
  };

  if (w <= qt) {
    const bf16* ka = kfb + (size_t)w * 2048 + lane * 8;
    a0 = *(const bf16x8*)(ka);
    a1 = *(const bf16x8*)(ka + 512);
    a2 = *(const bf16x8*)(ka + 1024);
    a3 = *(const bf16x8*)(ka + 1536);
    int diag = (w == (qt & 3)) ? 1 : 0;   // diag implies w <= qt
    int T = ((qt - w) >> 2) + 1 - diag;   // non-diag step count
    int kt = w;
    for (int i = 0; i < T; ++i, kt += 4) step(kt, false);
    if (diag) step(qt, true);
  }

  // ---- cross-wave combine: 2-round LDS tree (33-float stride: conflict-free) ----
  __shared__ float red[2][64][33];
  auto dump = [&](int slot) {
    float* d = &red[slot][lane][0];
#pragma unroll
    for (int r = 0; r < 16; ++r) { d[r] = o0[r]; d[16 + r] = o1[r]; }
    d[32] = lacc;
  };
  auto gather = [&](int slot) {
    const float* s = &red[slot][lane][0];
#pragma unroll
    for (int r = 0; r < 16; ++r) { o0[r] += s[r]; o1[r] += s[16 + r]; }
    lacc += s[32];
  };
  if (w >= 2) dump(w - 2);
  __syncthreads();
  if (w < 2) gather(w);
  __syncthreads();
  if (w == 1) dump(0);
  __syncthreads();
  if (w == 0) {
    gather(0);
    float ltot = lacc + __shfl_xor(lacc, 32);
    float linv = 1.0f / ltot;
#pragma unroll
    for (int r = 0; r < 16; ++r) {
      int qoff = (r & 3) + 8 * (r >> 2) + base4;
      float sc = __shfl(linv, qoff);
      size_t ob = ((size_t)(b * TSEQ + q0 + qoff)) * NC + h * HD + l31;
      out[ob]      = __float2bfloat16(o0[r] * sc);
      out[ob + 32] = __float2bfloat16(o1[r] * sc);
    }
  }
}

extern "C" void kernel_launch(void* const* d_in, const int* in_sizes, int n_in,
                              void* d_out, int out_size, void* d_ws, size_t ws_size,
                              hipStream_t stream) {
  const float* x     = (const float*)d_in[0];
  const float* ln1_g = (const float*)d_in[1];
  const float* ln1_b = (const float*)d_in[2];
  const float* Wq    = (const float*)d_in[3];
  const float* bq    = (const float*)d_in[4];
  const float* Wk    = (const float*)d_in[5];
  const float* bk    = (const float*)d_in[6];
  const float* Wv    = (const float*)d_in[7];
  const float* bv    = (const float*)d_in[8];
  const float* Wo    = (const float*)d_in[9];
  const float* bo    = (const float*)d_in[10];
  const float* ln2_g = (const float*)d_in[11];
  const float* ln2_b = (const float*)d_in[12];
  const float* W1    = (const float*)d_in[13];
  const float* b1    = (const float*)d_in[14];
  const float* W2    = (const float*)d_in[15];
  const float* b2    = (const float*)d_in[16];

  char* ws = (char*)d_ws;
  const size_t MB = 1u << 20;
  bf16* WqkvT = (bf16*)(ws + 0 * MB);   // 4x1024x1024 (q|k|v|o)
  bf16* W1T  = (bf16*)(ws + 8 * MB);    // 4096x1024
  bf16* W2T  = (bf16*)(ws + 16 * MB);   // 1024x4096
  bf16* xn1  = (bf16*)(ws + 24 * MB);   // 4096x1024
  bf16* qb   = (bf16*)(ws + 32 * MB);   // (b,h,t,d)        [dead after attn]
  bf16* kfB  = (bf16*)(ws + 40 * MB);   // K fragment layout [dead after attn]
  bf16* vfB  = (bf16*)(ws + 48 * MB);   // V fragment layout [dead after attn]
  bf16* att  = (bf16*)(ws + 56 * MB);   // 4096x1024        [dead after Wo gemm]
  float* x2  = (float*)(ws + 64 * MB);  // 4096x1024 fp32
  bf16* xn2  = (bf16*)(ws + 80 * MB);   // 4096x1024
  bf16* h1   = (bf16*)(ws + 88 * MB);   // 4096x4096        [written after woP consumed]
  bf16* woP  = (bf16*)(ws + 88 * MB);   // 2x 4096x1024 Wo partials (reuses h1 region)
  bf16* w2P  = (bf16*)(ws + 32 * MB);   // 4x 4096x1024 W2 partials (reuses q/k/v/att)
  bf16* WoT  = WqkvT + 3 * (size_t)NC * NC;

  transpose_all_kernel<<<12288, dim3(32, 8), 0, stream>>>(
      Wq, Wk, Wv, Wo, W1, W2, WqkvT, W1T, W2T);

  ln_cast_kernel<<<NROWS, 256, 0, stream>>>(x, ln1_g, ln1_b, xn1);

  gemm256<MODE_QKV><<<dim3(12, 16, 1), 512, 0, stream>>>(
      xn1, WqkvT, bq, bk, bv, qb, kfB, vfB, NROWS, 3 * NC, NC, NC);

  attn_kernel<<<2048, 256, 0, stream>>>(qb, kfB, vfB, att);

  gemm256<MODE_PART><<<dim3(4, 16, 2), 512, 0, stream>>>(
      att, WoT, nullptr, nullptr, nullptr, woP, nullptr, nullptr, NROWS, NC, NC, NC / 2);

  wo_ln_kernel<<<NROWS, 256, 0, stream>>>(x, bo, woP, ln2_g, ln2_b, x2, xn2);

  gemm256<MODE_GELU><<<dim3(16, 16, 1), 512, 0, stream>>>(
      xn2, W1T, b1, nullptr, nullptr, h1, nullptr, nullptr, NROWS, DFF, NC, NC);

  gemm256<MODE_PART><<<dim3(4, 16, 4), 512, 0, stream>>>(
      h1, W2T, nullptr, nullptr, nullptr, w2P, nullptr, nullptr, NROWS, NC, DFF, DFF / 4);

  w2_final_kernel<<<NROWS, 256, 0, stream>>>(x2, b2, w2P, (float*)d_out);
}

// Round 11
// 339.147 us; speedup vs baseline: 1.0597x; 1.0213x over previous
//
#include <hip/hip_runtime.h>
#include <hip/hip_bf16.h>

typedef __hip_bfloat16 bf16;
using bf16x8 = __attribute__((ext_vector_type(8))) short;
using f32x4  = __attribute__((ext_vector_type(4))) float;
using f32x16 = __attribute__((ext_vector_type(16))) float;
using u32x4  = __attribute__((ext_vector_type(4))) unsigned int;

#define TSEQ 2048
#define NH   16
#define HD   64
#define NC   1024
#define DFF  4096
#define NROWS 4096   // B*T

__device__ __forceinline__ float b2f(short s) {
  unsigned int u = ((unsigned int)(unsigned short)s) << 16;
  return __builtin_bit_cast(float, u);
}

// pack two f32 -> two bf16 (RNE), single instruction; dst.lo = a, dst.hi = b
__device__ __forceinline__ unsigned cvtpk(float a, float b) {
  unsigned r;
  asm("v_cvt_pk_bf16_f32 %0, %1, %2" : "=v"(r) : "v"(a), "v"(b));
  return r;
}

// v_permlane32_swap_b32 vdst, src: vdst[32:63] <-> src[0:31]
__device__ __forceinline__ void pl32swap(unsigned &d, unsigned &s) {
  asm("v_permlane32_swap_b32 %0, %1" : "+v"(d), "+v"(s));
}

// tanh-approx GELU via hw exp; |err| < ~1e-3 (vs exact-erf reference)
__device__ __forceinline__ float gelu_f(float x) {
  float u = 0.7978845608028654f * fmaf(0.044715f * x, x * x, x);
  float e = __expf(2.0f * u);
  float t = 1.0f - 2.0f / (e + 1.0f);   // tanh(u)
  return 0.5f * x * (1.0f + t);
}

// ---------------- LayerNorm (fp32 in) -> bf16 out ----------------
__global__ __launch_bounds__(256)
void ln_cast_kernel(const float* __restrict__ x, const float* __restrict__ g,
                    const float* __restrict__ b, bf16* __restrict__ out) {
  int row = blockIdx.x, tid = threadIdx.x;
  const float4 v = ((const float4*)(x + (size_t)row * NC))[tid];
  float s  = v.x + v.y + v.z + v.w;
  float s2 = v.x*v.x + v.y*v.y + v.z*v.z + v.w*v.w;
#pragma unroll
  for (int m = 1; m < 64; m <<= 1) { s += __shfl_xor(s, m); s2 += __shfl_xor(s2, m); }
  __shared__ float rs[4], rs2[4];
  if ((tid & 63) == 0) { rs[tid >> 6] = s; rs2[tid >> 6] = s2; }
  __syncthreads();
  s  = rs[0] + rs[1] + rs[2] + rs[3];
  s2 = rs2[0] + rs2[1] + rs2[2] + rs2[3];
  float mu   = s * (1.0f / NC);
  float var  = s2 * (1.0f / NC) - mu * mu;
  float rstd = rsqrtf(var + 1e-5f);
  const float4 gv = ((const float4*)g)[tid];
  const float4 bv = ((const float4*)b)[tid];
  bf16* o = out + (size_t)row * NC + tid * 4;
  o[0] = __float2bfloat16((v.x - mu) * rstd * gv.x + bv.x);
  o[1] = __float2bfloat16((v.y - mu) * rstd * gv.y + bv.y);
  o[2] = __float2bfloat16((v.z - mu) * rstd * gv.z + bv.z);
  o[3] = __float2bfloat16((v.w - mu) * rstd * gv.w + bv.w);
}

// ---- x2 = x + bo + P0 + P1 (bf16 partials); then LN(x2) -> xn2 (fused) ----
__global__ __launch_bounds__(256)
void wo_ln_kernel(const float* __restrict__ x, const float* __restrict__ bo,
                  const bf16* __restrict__ P, const float* __restrict__ g,
                  const float* __restrict__ bln, float* __restrict__ x2,
                  bf16* __restrict__ xn2) {
  int row = blockIdx.x, tid = threadIdx.x;
  size_t base = (size_t)row * NC + tid * 4;
  const float4 xv = *(const float4*)(x + base);
  const float4 bv = ((const float4*)bo)[tid];
  short4 p0 = *(const short4*)((const short*)P + base);
  short4 p1 = *(const short4*)((const short*)P + (size_t)NROWS * NC + base);
  float v0 = xv.x + bv.x + b2f(p0.x) + b2f(p1.x);
  float v1 = xv.y + bv.y + b2f(p0.y) + b2f(p1.y);
  float v2 = xv.z + bv.z + b2f(p0.z) + b2f(p1.z);
  float v3 = xv.w + bv.w + b2f(p0.w) + b2f(p1.w);
  float4 ov = {v0, v1, v2, v3};
  *(float4*)(x2 + base) = ov;
  float s  = v0 + v1 + v2 + v3;
  float s2 = v0*v0 + v1*v1 + v2*v2 + v3*v3;
#pragma unroll
  for (int m = 1; m < 64; m <<= 1) { s += __shfl_xor(s, m); s2 += __shfl_xor(s2, m); }
  __shared__ float rs[4], rs2[4];
  if ((tid & 63) == 0) { rs[tid >> 6] = s; rs2[tid >> 6] = s2; }
  __syncthreads();
  s  = rs[0] + rs[1] + rs[2] + rs[3];
  s2 = rs2[0] + rs2[1] + rs2[2] + rs2[3];
  float mu   = s * (1.0f / NC);
  float var  = s2 * (1.0f / NC) - mu * mu;
  float rstd = rsqrtf(var + 1e-5f);
  const float4 gv = ((const float4*)g)[tid];
  const float4 lv = ((const float4*)bln)[tid];
  bf16* o = xn2 + base;
  o[0] = __float2bfloat16((v0 - mu) * rstd * gv.x + lv.x);
  o[1] = __float2bfloat16((v1 - mu) * rstd * gv.y + lv.y);
  o[2] = __float2bfloat16((v2 - mu) * rstd * gv.z + lv.z);
  o[3] = __float2bfloat16((v3 - mu) * rstd * gv.w + lv.w);
}

// ---- d_out = x2 + b2 + sum of 4 bf16 partials ----
__global__ __launch_bounds__(256)
void w2_final_kernel(const float* __restrict__ x2, const float* __restrict__ b2,
                     const bf16* __restrict__ P, float* __restrict__ out) {
  int row = blockIdx.x, tid = threadIdx.x;
  size_t base = (size_t)row * NC + tid * 4;
  const float4 xv = *(const float4*)(x2 + base);
  const float4 bv = ((const float4*)b2)[tid];
  float a0 = xv.x + bv.x, a1 = xv.y + bv.y, a2 = xv.z + bv.z, a3 = xv.w + bv.w;
#pragma unroll
  for (int z = 0; z < 4; ++z) {
    short4 p = *(const short4*)((const short*)P + (size_t)z * NROWS * NC + base);
    a0 += b2f(p.x); a1 += b2f(p.y); a2 += b2f(p.z); a3 += b2f(p.w);
  }
  float4 ov = {a0, a1, a2, a3};
  *(float4*)(out + base) = ov;
}

// ---------------- all weight transposes in one launch ----------------
__global__ __launch_bounds__(256)
void transpose_all_kernel(const float* __restrict__ Wq, const float* __restrict__ Wk,
                          const float* __restrict__ Wv, const float* __restrict__ Wo,
                          const float* __restrict__ W1, const float* __restrict__ W2,
                          bf16* __restrict__ WqkvoT, bf16* __restrict__ W1T,
                          bf16* __restrict__ W2T) {
  int bid = blockIdx.x;
  const float* W; bf16* Wt; int K, N, nx, tile;
  if (bid < 4096) {
    int z = bid >> 10; tile = bid & 1023;
    W = (z == 0) ? Wq : (z == 1) ? Wk : (z == 2) ? Wv : Wo;
    Wt = WqkvoT + (size_t)z * NC * NC; K = NC; N = NC; nx = 32;
  } else if (bid < 8192) {
    tile = bid - 4096; W = W1; Wt = W1T; K = NC; N = DFF; nx = 128;
  } else {
    tile = bid - 8192; W = W2; Wt = W2T; K = DFF; N = NC; nx = 32;
  }
  int n0 = (tile % nx) * 32, k0 = (tile / nx) * 32;
  __shared__ float t[32][33];
  int tx = threadIdx.x, ty = threadIdx.y;  // 32 x 8
#pragma unroll
  for (int i = 0; i < 4; ++i)
    t[ty + i * 8][tx] = W[(size_t)(k0 + ty + i * 8) * N + n0 + tx];
  __syncthreads();
#pragma unroll
  for (int i = 0; i < 4; ++i)
    Wt[(size_t)(n0 + ty + i * 8) * K + k0 + tx] = __float2bfloat16(t[tx][ty + i * 8]);
}

// ---------------- GEMM v5: 256x256, 8 waves, reg-staged, 1-barrier/tile ----------------
// C(MxN) = A(MxK,bf16) @ Bt(NxK,bf16)^T. BK=32, double-buffered LDS (64KB).
// Fix for the TA bottleneck: v3/v4 used global_load_lds whose per-lane sources were
// strided by K (64 cache lines PER INSTRUCTION -> ~2048 line-transactions/CU/tile,
// 2x the MFMA time). Now: coalesced global_load_dwordx4 to regs (4 lanes/row x 16
// rows = 16 lines/instr, the minimum) + ds_write_b128 scatter into lane-major
// fragment blocks (writes max 4-way conflict; fragment ds_reads stay ZERO-conflict:
// block (g*2+ks)*512 elems, lane l's 16B at +l*16).
// Loop: ONE barrier per K-tile. Write buf[(t+1)&1] while reading buf[t&1]; wave
// drift <= 1 iter => no WAR across parities. Loads get a full iteration of latency
// cover; compiler emits fine-grained lgkmcnt for ds_read->MFMA (m97-verified).
#define MODE_GELU 4
#define MODE_QKV  5
#define MODE_PART 6

template <int MODE>
__global__ __launch_bounds__(512, 2)
void gemm256(const bf16* __restrict__ A, const bf16* __restrict__ Bt,
             const float* __restrict__ bias, const float* __restrict__ bias2,
             const float* __restrict__ bias3,
             void* __restrict__ outp, void* __restrict__ out2, void* __restrict__ out3,
             int M, int N, int K, int KS) {
  __shared__ bf16 lds[32768];   // A: 2 bufs x 8192 elems; B: +16384
  int tid  = threadIdx.x;
  int w    = tid >> 6;
  int lane = tid & 63;
  int l31  = lane & 31;
  int kb   = lane >> 5;          // k-half of fragment
  int wm   = w >> 2, wn = w & 3; // 2x4 wave grid; wave tile 128x64

  // block swizzle (GROUP_M = 4, col-major within group)
  int gN = gridDim.x, gM = gridDim.y;
  int pid = blockIdx.y * gN + blockIdx.x;
  int npg = 4 * gN;
  int gid = pid / npg;
  int fm  = gid * 4;
  int gsz = min(gM - fm, 4);
  int bm = (fm + (pid % gsz)) * 256;
  int bn = ((pid % npg) / gsz) * 256;
  int k_beg = blockIdx.z * KS;

  // reg-staging: wave w owns rows [w*32, w*32+32). lane l: row-in-instr q = l>>2,
  // chunk c = l&3 (8 elems). Coalesced source: 4 lanes x 16B per row.
  int c = lane & 3;
  int q = lane >> 2;
  const bf16* gA = A  + (size_t)(bm + w * 32 + q) * K + k_beg + c * 8;
  const bf16* gB = Bt + (size_t)(bn + w * 32 + q) * K + k_beg + c * 8;
  // LDS write target (lane-major frag block): elem (w*2 + (c>>1))*512 + ((c&1)*32+q)*8
  int wr = (w * 2 + (c >> 1)) * 512 + ((c & 1) * 32 + q) * 8;

  bf16x8 ra0, ra1, rb0, rb1;
  ra0 = *(const bf16x8*)(gA);
  ra1 = *(const bf16x8*)(gA + (size_t)16 * K);
  rb0 = *(const bf16x8*)(gB);
  rb1 = *(const bf16x8*)(gB + (size_t)16 * K);

  f32x16 acc[4][2];
#pragma unroll
  for (int mi = 0; mi < 4; ++mi)
#pragma unroll
    for (int ni = 0; ni < 2; ++ni)
#pragma unroll
      for (int r = 0; r < 16; ++r) acc[mi][ni][r] = 0.f;

  int NT = KS >> 5;
  for (int t = 0; t < NT; ++t) {
    bf16* dA = &lds[(t & 1) * 8192];
    bf16* dB = &lds[16384 + (t & 1) * 8192];
    // scatter staged tile t into LDS (compiler waits vmcnt for regs)
    *(bf16x8*)(dA + wr)       = ra0;
    *(bf16x8*)(dA + wr + 128) = ra1;   // +16 rows
    *(bf16x8*)(dB + wr)       = rb0;
    *(bf16x8*)(dB + wr + 128) = rb1;
    if (t + 1 < NT) {                  // prefetch tile t+1 (lands under this tile's MFMA)
      size_t ko = (size_t)(t + 1) * 32;
      ra0 = *(const bf16x8*)(gA + ko);
      ra1 = *(const bf16x8*)(gA + ko + (size_t)16 * K);
      rb0 = *(const bf16x8*)(gB + ko);
      rb1 = *(const bf16x8*)(gB + ko + (size_t)16 * K);
    }
    __builtin_amdgcn_sched_barrier(0);
    asm volatile("s_waitcnt lgkmcnt(0)" ::: "memory");   // all ds_writes done
    __builtin_amdgcn_s_barrier();
    __builtin_amdgcn_sched_barrier(0);

    const bf16* bufA = &lds[(t & 1) * 8192];
    const bf16* bufB = &lds[16384 + (t & 1) * 8192];
    bf16x8 af[2][4], bfr[2][2];
#pragma unroll
    for (int ks = 0; ks < 2; ++ks) {
#pragma unroll
      for (int mi = 0; mi < 4; ++mi)
        af[ks][mi] = *(const bf16x8*)&bufA[((wm * 4 + mi) * 2 + ks) * 512 + lane * 8];
#pragma unroll
      for (int ni = 0; ni < 2; ++ni)
        bfr[ks][ni] = *(const bf16x8*)&bufB[((wn * 2 + ni) * 2 + ks) * 512 + lane * 8];
    }
    __builtin_amdgcn_s_setprio(1);
#pragma unroll
    for (int ks = 0; ks < 2; ++ks)
#pragma unroll
      for (int mi = 0; mi < 4; ++mi)
#pragma unroll
        for (int ni = 0; ni < 2; ++ni)
          acc[mi][ni] = __builtin_amdgcn_mfma_f32_32x32x16_bf16(af[ks][mi], bfr[ks][ni], acc[mi][ni], 0, 0, 0);
    __builtin_amdgcn_s_setprio(0);
  }

  // ---- epilogues (C: col = l31 of B-frag, row = (reg&3)+8*(reg>>2)+4*kb) ----
  if (MODE == MODE_PART) {
    bf16* dst = (bf16*)outp + (size_t)blockIdx.z * M * N;
#pragma unroll
    for (int mi = 0; mi < 4; ++mi)
#pragma unroll
      for (int ni = 0; ni < 2; ++ni) {
        int col = bn + wn * 64 + ni * 32 + l31;
#pragma unroll
        for (int reg = 0; reg < 16; ++reg) {
          int row = bm + wm * 128 + mi * 32 + (reg & 3) + 8 * (reg >> 2) + 4 * kb;
          dst[(size_t)row * N + col] = __float2bfloat16(acc[mi][ni][reg]);
        }
      }
  } else if (MODE == MODE_GELU) {
    float bcol[2];
#pragma unroll
    for (int ni = 0; ni < 2; ++ni) bcol[ni] = bias[bn + wn * 64 + ni * 32 + l31];
#pragma unroll
    for (int mi = 0; mi < 4; ++mi)
#pragma unroll
      for (int ni = 0; ni < 2; ++ni) {
        int col = bn + wn * 64 + ni * 32 + l31;
#pragma unroll
        for (int reg = 0; reg < 16; ++reg) {
          int row = bm + wm * 128 + mi * 32 + (reg & 3) + 8 * (reg >> 2) + 4 * kb;
          ((bf16*)outp)[(size_t)row * N + col] =
              __float2bfloat16(gelu_f(acc[mi][ni][reg] + bcol[ni]));
        }
      }
  } else {  // MODE_QKV: seg block-uniform; q -> (b,h,t,d); k -> Kf frag; v -> Vf frag
    int seg = bn >> 10;
    int c1b = (bn & (NC - 1)) + wn * 64;
    const float* bp = (seg == 0) ? bias : (seg == 1) ? bias2 : bias3;
    float bcol[2]; int hh[2], dd[2];
#pragma unroll
    for (int ni = 0; ni < 2; ++ni) {
      int c1 = c1b + ni * 32 + l31;
      bcol[ni] = bp[c1]; hh[ni] = c1 >> 6; dd[ni] = c1 & (HD - 1);
    }
    if (seg == 0) {
      bf16* dst = (bf16*)outp;
#pragma unroll
      for (int mi = 0; mi < 4; ++mi)
#pragma unroll
        for (int reg = 0; reg < 16; ++reg) {
          int row = bm + wm * 128 + mi * 32 + (reg & 3) + 8 * (reg >> 2) + 4 * kb;
          int bbi = row >> 11, t = row & (TSEQ - 1);
#pragma unroll
          for (int ni = 0; ni < 2; ++ni)
            dst[((size_t)(bbi * NH + hh[ni]) * TSEQ + t) * HD + dd[ni]] =
                __float2bfloat16(acc[mi][ni][reg] + bcol[ni]);
        }
    } else if (seg == 1) {
      // Kf[bh][kt(64)][ds(4)][lane(64)][8]
      bf16* dst = (bf16*)out2;
#pragma unroll
      for (int mi = 0; mi < 4; ++mi)
#pragma unroll
        for (int reg = 0; reg < 16; ++reg) {
          int row = bm + wm * 128 + mi * 32 + (reg & 3) + 8 * (reg >> 2) + 4 * kb;
          int bbi = row >> 11, t = row & (TSEQ - 1);
          int kt = t >> 5, lk = t & 31;
#pragma unroll
          for (int ni = 0; ni < 2; ++ni) {
            int d = dd[ni];
            size_t off = ((((size_t)(bbi * NH + hh[ni]) * 64 + kt) * 4 + (d >> 4)) * 64
                          + ((d >> 3) & 1) * 32 + lk) * 8 + (d & 7);
            dst[off] = __float2bfloat16(acc[mi][ni][reg] + bcol[ni]);
          }
        }
    } else {
      // Vf[bh][kt(64)][dt(2)][ks(2)][lane(64)][8]
      bf16* dst = (bf16*)out3;
#pragma unroll
      for (int mi = 0; mi < 4; ++mi)
#pragma unroll
        for (int reg = 0; reg < 16; ++reg) {
          int row = bm + wm * 128 + mi * 32 + (reg & 3) + 8 * (reg >> 2) + 4 * kb;
          int bbi = row >> 11, t = row & (TSEQ - 1);
          int kt = t >> 5, rem = t & 31;
          int ks = rem >> 4, hf = (rem >> 3) & 1, j = rem & 7;
#pragma unroll
          for (int ni = 0; ni < 2; ++ni) {
            int d = dd[ni];
            size_t off = (((((size_t)(bbi * NH + hh[ni]) * 64 + kt) * 2 + (d >> 5)) * 2 + ks) * 64
                          + hf * 32 + (d & 31)) * 8 + j;
            dst[off] = __float2bfloat16(acc[mi][ni][reg] + bcol[ni]);
          }
        }
    }
  }
}

// ---------------- Flash attention v6: swapped-QK^T 32x32, split-K x4, frag-layout K/V ----
__global__ __launch_bounds__(256)
void attn_kernel(const bf16* __restrict__ q, const bf16* __restrict__ kf,
                 const bf16* __restrict__ vf, bf16* __restrict__ out) {
  int id  = blockIdx.x;            // 0..2047
  int xcd = id & 7;
  int t   = id >> 3;               // per-XCD arrival index 0..255
  int bh  = xcd * 4 + (t & 3);
  int u   = t >> 2;                // 0..63
  int qt  = (u < 32) ? (2 * u) : (63 - 2 * (u - 32));
  int b = bh >> 4, h = bh & 15;

  int tid  = threadIdx.x;
  int w    = tid >> 6;             // split-K wave 0..3
  int lane = tid & 63;
  int l31  = lane & 31;
  int hh   = lane >> 5;            // 0/1
  int h8   = hh * 8;
  int base4 = hh * 4;

  const bf16* qp  = q  + (size_t)(b * NH + h) * TSEQ * HD;
  const bf16* kfb = kf + (size_t)bh * (64 * 4 * 64 * 8);   // 256KB per (b,h)
  const bf16* vfb = vf + (size_t)bh * (64 * 2 * 2 * 64 * 8);

  int q0 = qt * 32;

  // Q fragments (B-operand): lane holds Q[q0+l31][ds*16 + h8 .. +7]
  bf16x8 qf[4];
#pragma unroll
  for (int ds = 0; ds < 4; ++ds)
    qf[ds] = *(const bf16x8*)(qp + (size_t)(q0 + l31) * HD + ds * 16 + h8);

  f32x16 o0, o1;
#pragma unroll
  for (int r = 0; r < 16; ++r) { o0[r] = 0.f; o1[r] = 0.f; }
  float lacc = 0.f;

  bf16x8 a0, a1, a2, a3;           // K fragments (A-operand), pipelined

  auto step = [&](int kt, bool dg) {
    const bf16* vs = vfb + (size_t)kt * 2048 + lane * 8;
    bf16x8 v00 = *(const bf16x8*)(vs);            // dt0 ks0
    bf16x8 v01 = *(const bf16x8*)(vs + 512);      // dt0 ks1
    bf16x8 v10 = *(const bf16x8*)(vs + 1024);     // dt1 ks0
    bf16x8 v11 = *(const bf16x8*)(vs + 1536);     // dt1 ks1
    bf16x8 n0, n1, n2, n3;
    bool pf = !dg && (kt + 4 <= qt);
    if (pf) {
      const bf16* kn = kfb + (size_t)(kt + 4) * 2048 + lane * 8;
      n0 = *(const bf16x8*)(kn);
      n1 = *(const bf16x8*)(kn + 512);
      n2 = *(const bf16x8*)(kn + 1024);
      n3 = *(const bf16x8*)(kn + 1536);
    }

    f32x16 c;
#pragma unroll
    for (int r = 0; r < 16; ++r) c[r] = 0.f;
    c = __builtin_amdgcn_mfma_f32_32x32x16_bf16(a0, qf[0], c, 0, 0, 0);
    c = __builtin_amdgcn_mfma_f32_32x32x16_bf16(a1, qf[1], c, 0, 0, 0);
    c = __builtin_amdgcn_mfma_f32_32x32x16_bf16(a2, qf[2], c, 0, 0, 0);
    c = __builtin_amdgcn_mfma_f32_32x32x16_bf16(a3, qf[3], c, 0, 0, 0);

    float p[16];
    float ls = 0.f;
#pragma unroll
    for (int r = 0; r < 16; ++r) {
      float pv = exp2f(fmaf(c[r], 0.18033688011112042f, -11.541560327111707f));
      if (dg) {
        int krr = (r & 3) + 8 * (r >> 2) + base4;
        pv = (krr <= l31) ? pv : 0.f;
      }
      p[r] = pv;
      ls += pv;
    }
    lacc += ls;

    unsigned A0 = cvtpk(p[0],  p[1]),  C0 = cvtpk(p[4],  p[5]);
    unsigned B0 = cvtpk(p[2],  p[3]),  D0 = cvtpk(p[6],  p[7]);
    pl32swap(A0, C0); pl32swap(B0, D0);
    unsigned A1 = cvtpk(p[8],  p[9]),  C1 = cvtpk(p[12], p[13]);
    unsigned B1 = cvtpk(p[10], p[11]), D1 = cvtpk(p[14], p[15]);
    pl32swap(A1, C1); pl32swap(B1, D1);
    u32x4 w0v = {A0, B0, C0, D0};
    u32x4 w1v = {A1, B1, C1, D1};
    bf16x8 pa0 = __builtin_bit_cast(bf16x8, w0v);
    bf16x8 pa1 = __builtin_bit_cast(bf16x8, w1v);

    o0 = __builtin_amdgcn_mfma_f32_32x32x16_bf16(pa0, v00, o0, 0, 0, 0);
    o0 = __builtin_amdgcn_mfma_f32_32x32x16_bf16(pa1, v01, o0, 0, 0, 0);
    o1 = __builtin_amdgcn_mfma_f32_32x32x16_bf16(pa0, v10, o1, 0, 0, 0);
    o1 = __builtin_amdgcn_mfma_f32_32x32x16_bf16(pa1, v11, o1, 0, 0, 0);

    if (pf) { a0 = n0; a1 = n1; a2 = n2; a3 = n3; }
  };

  if (w <= qt) {
    const bf16* ka = kfb + (size_t)w * 2048 + lane * 8;
    a0 = *(const bf16x8*)(ka);
    a1 = *(const bf16x8*)(ka + 512);
    a2 = *(const bf16x8*)(ka + 1024);
    a3 = *(const bf16x8*)(ka + 1536);
    int diag = (w == (qt & 3)) ? 1 : 0;   // diag implies w <= qt
    int T = ((qt - w) >> 2) + 1 - diag;   // non-diag step count
    int kt = w;
    for (int i = 0; i < T; ++i, kt += 4) step(kt, false);
    if (diag) step(qt, true);
  }

  // ---- cross-wave combine: 2-round LDS tree (33-float stride: conflict-free) ----
  __shared__ float red[2][64][33];
  auto dump = [&](int slot) {
    float* d = &red[slot][lane][0];
#pragma unroll
    for (int r = 0; r < 16; ++r) { d[r] = o0[r]; d[16 + r] = o1[r]; }
    d[32] = lacc;
  };
  auto gather = [&](int slot) {
    const float* s = &red[slot][lane][0];
#pragma unroll
    for (int r = 0; r < 16; ++r) { o0[r] += s[r]; o1[r] += s[16 + r]; }
    lacc += s[32];
  };
  if (w >= 2) dump(w - 2);
  __syncthreads();
  if (w < 2) gather(w);
  __syncthreads();
  if (w == 1) dump(0);
  __syncthreads();
  if (w == 0) {
    gather(0);
    float ltot = lacc + __shfl_xor(lacc, 32);
    float linv = 1.0f / ltot;
#pragma unroll
    for (int r = 0; r < 16; ++r) {
      int qoff = (r & 3) + 8 * (r >> 2) + base4;
      float sc = __shfl(linv, qoff);
      size_t ob = ((size_t)(b * TSEQ + q0 + qoff)) * NC + h * HD + l31;
      out[ob]      = __float2bfloat16(o0[r] * sc);
      out[ob + 32] = __float2bfloat16(o1[r] * sc);
    }
  }
}

extern "C" void kernel_launch(void* const* d_in, const int* in_sizes, int n_in,
                              void* d_out, int out_size, void* d_ws, size_t ws_size,
                              hipStream_t stream) {
  const float* x     = (const float*)d_in[0];
  const float* ln1_g = (const float*)d_in[1];
  const float* ln1_b = (const float*)d_in[2];
  const float* Wq    = (const float*)d_in[3];
  const float* bq    = (const float*)d_in[4];
  const float* Wk    = (const float*)d_in[5];
  const float* bk    = (const float*)d_in[6];
  const float* Wv    = (const float*)d_in[7];
  const float* bv    = (const float*)d_in[8];
  const float* Wo    = (const float*)d_in[9];
  const float* bo    = (const float*)d_in[10];
  const float* ln2_g = (const float*)d_in[11];
  const float* ln2_b = (const float*)d_in[12];
  const float* W1    = (const float*)d_in[13];
  const float* b1    = (const float*)d_in[14];
  const float* W2    = (const float*)d_in[15];
  const float* b2    = (const float*)d_in[16];

  char* ws = (char*)d_ws;
  const size_t MB = 1u << 20;
  bf16* WqkvT = (bf16*)(ws + 0 * MB);   // 4x1024x1024 (q|k|v|o)
  bf16* W1T  = (bf16*)(ws + 8 * MB);    // 4096x1024
  bf16* W2T  = (bf16*)(ws + 16 * MB);   // 1024x4096
  bf16* xn1  = (bf16*)(ws + 24 * MB);   // 4096x1024
  bf16* qb   = (bf16*)(ws + 32 * MB);   // (b,h,t,d)        [dead after attn]
  bf16* kfB  = (bf16*)(ws + 40 * MB);   // K fragment layout [dead after attn]
  bf16* vfB  = (bf16*)(ws + 48 * MB);   // V fragment layout [dead after attn]
  bf16* att  = (bf16*)(ws + 56 * MB);   // 4096x1024        [dead after Wo gemm]
  float* x2  = (float*)(ws + 64 * MB);  // 4096x1024 fp32
  bf16* xn2  = (bf16*)(ws + 80 * MB);   // 4096x1024
  bf16* h1   = (bf16*)(ws + 88 * MB);   // 4096x4096        [written after woP consumed]
  bf16* woP  = (bf16*)(ws + 88 * MB);   // 2x 4096x1024 Wo partials (reuses h1 region)
  bf16* w2P  = (bf16*)(ws + 32 * MB);   // 4x 4096x1024 W2 partials (reuses q/k/v/att)
  bf16* WoT  = WqkvT + 3 * (size_t)NC * NC;

  transpose_all_kernel<<<12288, dim3(32, 8), 0, stream>>>(
      Wq, Wk, Wv, Wo, W1, W2, WqkvT, W1T, W2T);

  ln_cast_kernel<<<NROWS, 256, 0, stream>>>(x, ln1_g, ln1_b, xn1);

  gemm256<MODE_QKV><<<dim3(12, 16, 1), 512, 0, stream>>>(
      xn1, WqkvT, bq, bk, bv, qb, kfB, vfB, NROWS, 3 * NC, NC, NC);

  attn_kernel<<<2048, 256, 0, stream>>>(qb, kfB, vfB, att);

  gemm256<MODE_PART><<<dim3(4, 16, 2), 512, 0, stream>>>(
      att, WoT, nullptr, nullptr, nullptr, woP, nullptr, nullptr, NROWS, NC, NC, NC / 2);

  wo_ln_kernel<<<NROWS, 256, 0, stream>>>(x, bo, woP, ln2_g, ln2_b, x2, xn2);

  gemm256<MODE_GELU><<<dim3(16, 16, 1), 512, 0, stream>>>(
      xn2, W1T, b1, nullptr, nullptr, h1, nullptr, nullptr, NROWS, DFF, NC, NC);

  gemm256<MODE_PART><<<dim3(4, 16, 4), 512, 0, stream>>>(
      h1, W2T, nullptr, nullptr, nullptr, w2P, nullptr, nullptr, NROWS, NC, DFF, DFF / 4);

  w2_final_kernel<<<NROWS, 256, 0, stream>>>(x2, b2, w2P, (float*)d_out);
}

// Round 12
// 333.677 us; speedup vs baseline: 1.0771x; 1.0164x over previous
//
#include <hip/hip_runtime.h>
#include <hip/hip_bf16.h>

typedef __hip_bfloat16 bf16;
using bf16x8 = __attribute__((ext_vector_type(8))) short;
using f32x4  = __attribute__((ext_vector_type(4))) float;
using f32x16 = __attribute__((ext_vector_type(16))) float;
using u32x4  = __attribute__((ext_vector_type(4))) unsigned int;

#define TSEQ 2048
#define NH   16
#define HD   64
#define NC   1024
#define DFF  4096
#define NROWS 4096   // B*T

__device__ __forceinline__ float b2f(short s) {
  unsigned int u = ((unsigned int)(unsigned short)s) << 16;
  return __builtin_bit_cast(float, u);
}

// pack two f32 -> two bf16 (RNE), single instruction; dst.lo = a, dst.hi = b
__device__ __forceinline__ unsigned cvtpk(float a, float b) {
  unsigned r;
  asm("v_cvt_pk_bf16_f32 %0, %1, %2" : "=v"(r) : "v"(a), "v"(b));
  return r;
}

// v_permlane32_swap_b32 vdst, src: vdst[32:63] <-> src[0:31]
__device__ __forceinline__ void pl32swap(unsigned &d, unsigned &s) {
  asm("v_permlane32_swap_b32 %0, %1" : "+v"(d), "+v"(s));
}

// tanh-approx GELU via hw exp; |err| < ~1e-3 (vs exact-erf reference)
__device__ __forceinline__ float gelu_f(float x) {
  float u = 0.7978845608028654f * fmaf(0.044715f * x, x * x, x);
  float e = __expf(2.0f * u);
  float t = 1.0f - 2.0f / (e + 1.0f);   // tanh(u)
  return 0.5f * x * (1.0f + t);
}

// ---------------- LayerNorm (fp32 in) -> bf16 out ----------------
__global__ __launch_bounds__(256)
void ln_cast_kernel(const float* __restrict__ x, const float* __restrict__ g,
                    const float* __restrict__ b, bf16* __restrict__ out) {
  int row = blockIdx.x, tid = threadIdx.x;
  const float4 v = ((const float4*)(x + (size_t)row * NC))[tid];
  float s  = v.x + v.y + v.z + v.w;
  float s2 = v.x*v.x + v.y*v.y + v.z*v.z + v.w*v.w;
#pragma unroll
  for (int m = 1; m < 64; m <<= 1) { s += __shfl_xor(s, m); s2 += __shfl_xor(s2, m); }
  __shared__ float rs[4], rs2[4];
  if ((tid & 63) == 0) { rs[tid >> 6] = s; rs2[tid >> 6] = s2; }
  __syncthreads();
  s  = rs[0] + rs[1] + rs[2] + rs[3];
  s2 = rs2[0] + rs2[1] + rs2[2] + rs2[3];
  float mu   = s * (1.0f / NC);
  float var  = s2 * (1.0f / NC) - mu * mu;
  float rstd = rsqrtf(var + 1e-5f);
  const float4 gv = ((const float4*)g)[tid];
  const float4 bv = ((const float4*)b)[tid];
  bf16* o = out + (size_t)row * NC + tid * 4;
  o[0] = __float2bfloat16((v.x - mu) * rstd * gv.x + bv.x);
  o[1] = __float2bfloat16((v.y - mu) * rstd * gv.y + bv.y);
  o[2] = __float2bfloat16((v.z - mu) * rstd * gv.z + bv.z);
  o[3] = __float2bfloat16((v.w - mu) * rstd * gv.w + bv.w);
}

// ---- x2 = x + bo + P0 + P1 (bf16 partials); then LN(x2) -> xn2 (fused) ----
__global__ __launch_bounds__(256)
void wo_ln_kernel(const float* __restrict__ x, const float* __restrict__ bo,
                  const bf16* __restrict__ P, const float* __restrict__ g,
                  const float* __restrict__ bln, float* __restrict__ x2,
                  bf16* __restrict__ xn2) {
  int row = blockIdx.x, tid = threadIdx.x;
  size_t base = (size_t)row * NC + tid * 4;
  const float4 xv = *(const float4*)(x + base);
  const float4 bv = ((const float4*)bo)[tid];
  short4 p0 = *(const short4*)((const short*)P + base);
  short4 p1 = *(const short4*)((const short*)P + (size_t)NROWS * NC + base);
  float v0 = xv.x + bv.x + b2f(p0.x) + b2f(p1.x);
  float v1 = xv.y + bv.y + b2f(p0.y) + b2f(p1.y);
  float v2 = xv.z + bv.z + b2f(p0.z) + b2f(p1.z);
  float v3 = xv.w + bv.w + b2f(p0.w) + b2f(p1.w);
  float4 ov = {v0, v1, v2, v3};
  *(float4*)(x2 + base) = ov;
  float s  = v0 + v1 + v2 + v3;
  float s2 = v0*v0 + v1*v1 + v2*v2 + v3*v3;
#pragma unroll
  for (int m = 1; m < 64; m <<= 1) { s += __shfl_xor(s, m); s2 += __shfl_xor(s2, m); }
  __shared__ float rs[4], rs2[4];
  if ((tid & 63) == 0) { rs[tid >> 6] = s; rs2[tid >> 6] = s2; }
  __syncthreads();
  s  = rs[0] + rs[1] + rs[2] + rs[3];
  s2 = rs2[0] + rs2[1] + rs2[2] + rs2[3];
  float mu   = s * (1.0f / NC);
  float var  = s2 * (1.0f / NC) - mu * mu;
  float rstd = rsqrtf(var + 1e-5f);
  const float4 gv = ((const float4*)g)[tid];
  const float4 lv = ((const float4*)bln)[tid];
  bf16* o = xn2 + base;
  o[0] = __float2bfloat16((v0 - mu) * rstd * gv.x + lv.x);
  o[1] = __float2bfloat16((v1 - mu) * rstd * gv.y + lv.y);
  o[2] = __float2bfloat16((v2 - mu) * rstd * gv.z + lv.z);
  o[3] = __float2bfloat16((v3 - mu) * rstd * gv.w + lv.w);
}

// ---- d_out = x2 + b2 + sum of 4 bf16 partials ----
__global__ __launch_bounds__(256)
void w2_final_kernel(const float* __restrict__ x2, const float* __restrict__ b2,
                     const bf16* __restrict__ P, float* __restrict__ out) {
  int row = blockIdx.x, tid = threadIdx.x;
  size_t base = (size_t)row * NC + tid * 4;
  const float4 xv = *(const float4*)(x2 + base);
  const float4 bv = ((const float4*)b2)[tid];
  float a0 = xv.x + bv.x, a1 = xv.y + bv.y, a2 = xv.z + bv.z, a3 = xv.w + bv.w;
#pragma unroll
  for (int z = 0; z < 4; ++z) {
    short4 p = *(const short4*)((const short*)P + (size_t)z * NROWS * NC + base);
    a0 += b2f(p.x); a1 += b2f(p.y); a2 += b2f(p.z); a3 += b2f(p.w);
  }
  float4 ov = {a0, a1, a2, a3};
  *(float4*)(out + base) = ov;
}

// -------- all weight transposes -> B-FRAGMENT layout, one launch --------
// Bf[g(32-col group)][kt][ks][lane(kb*32+n31)][8]: lane kb*32+n31 holds
// W[k = kt*32+ks*16+kb*8+j][n = g*32+n31]. NKT = K/32.
__global__ __launch_bounds__(256)
void transpose_all_kernel(const float* __restrict__ Wq, const float* __restrict__ Wk,
                          const float* __restrict__ Wv, const float* __restrict__ Wo,
                          const float* __restrict__ W1, const float* __restrict__ W2,
                          bf16* __restrict__ WqkvoT, bf16* __restrict__ W1T,
                          bf16* __restrict__ W2T) {
  int bid = blockIdx.x;
  const float* W; bf16* Wt; int K, N, nx, tile;
  if (bid < 4096) {
    int z = bid >> 10; tile = bid & 1023;
    W = (z == 0) ? Wq : (z == 1) ? Wk : (z == 2) ? Wv : Wo;
    Wt = WqkvoT + (size_t)z * NC * NC; K = NC; N = NC; nx = 32;
  } else if (bid < 8192) {
    tile = bid - 4096; W = W1; Wt = W1T; K = NC; N = DFF; nx = 128;
  } else {
    tile = bid - 8192; W = W2; Wt = W2T; K = DFF; N = NC; nx = 32;
  }
  int n0 = (tile % nx) * 32, k0 = (tile / nx) * 32;
  __shared__ float t[32][33];
  int tx = threadIdx.x, ty = threadIdx.y;  // 32 x 8
#pragma unroll
  for (int i = 0; i < 4; ++i)
    t[ty + i * 8][tx] = W[(size_t)(k0 + ty + i * 8) * N + n0 + tx];
  __syncthreads();
  int NKT = K >> 5;
#pragma unroll
  for (int i = 0; i < 4; ++i) {
    int n = n0 + ty + i * 8, k = k0 + tx;
    size_t off = ((((size_t)((n >> 5) * NKT + (k >> 5)) * 2 + ((k >> 4) & 1)) * 64)
                  + ((k >> 3) & 1) * 32 + (n & 31)) * 8 + (k & 7);
    Wt[off] = __float2bfloat16(t[tx][ty + i * 8]);
  }
}

// ---------------- GEMM v6: 256x256, 8 waves, A-in-LDS (swizzled), B-direct ----------------
// C = A(MxK) @ Bf^T. BK=32, A double-buffered in 32KB LDS; B fragments loaded
// DIRECTLY from global frag layout (1KB coalesced per instr, L2-resident,
// prefetched 1 tile ahead into regs) -> LDS traffic/tile drops 128KB -> 80KB.
// A LDS uses both-sides XOR swizzle (byte ^= ((b>>9)&1)<<5 | ((b>>10)&1)<<6):
// writes AND reads bank-conflict-free (v5 writes were 4-way, 6.29M cyc/dispatch).
#define MODE_GELU 4
#define MODE_QKV  5
#define MODE_PART 6

template <int MODE>
__global__ __launch_bounds__(512, 2)
void gemm256(const bf16* __restrict__ A, const bf16* __restrict__ Bf,
             const float* __restrict__ bias, const float* __restrict__ bias2,
             const float* __restrict__ bias3,
             void* __restrict__ outp, void* __restrict__ out2, void* __restrict__ out3,
             int M, int N, int K, int KS) {
  __shared__ bf16 lds[16384];   // A only: 2 bufs x 8192 elems
  int tid  = threadIdx.x;
  int w    = tid >> 6;
  int lane = tid & 63;
  int l31  = lane & 31;
  int kb   = lane >> 5;          // k-half of fragment
  int wm   = w >> 2, wn = w & 3; // 2x4 wave grid; wave tile 128x64

  // block swizzle (GROUP_M = 4, col-major within group)
  int gN = gridDim.x, gM = gridDim.y;
  int pid = blockIdx.y * gN + blockIdx.x;
  int npg = 4 * gN;
  int gid = pid / npg;
  int fm  = gid * 4;
  int gsz = min(gM - fm, 4);
  int bm = (fm + (pid % gsz)) * 256;
  int bn = ((pid % npg) / gsz) * 256;
  int k_beg = blockIdx.z * KS;

  // ---- A reg-staging (rows w*32..w*32+31): lane l = (c=l&3, q=l>>2) ----
  int c = lane & 3;
  int q = lane >> 2;
  const bf16* gA = A + (size_t)(bm + w * 32 + q) * K + k_beg + c * 8;
  // LDS write elem offset, swizzled: base slot (c&1)*32+q in block w*2+(c>>1);
  // elem XOR key = ((c&1)<<4)|((c>>1)<<5)  (byte bits 5,6)
  int wrE = (((w * 2 + (c >> 1)) * 512 + ((c & 1) * 32 + q) * 8))
            ^ (((c & 1) << 4) | ((c >> 1) << 5));
  // read swizzle per-lane constants (byte ^= ((l>>5)<<5), elems):
  int lrE = (lane * 8) ^ ((lane >> 5) << 4);
  int lrO = lrE ^ 32;            // block-odd adds byte bit10 -> XOR 64B = 32 elems

  // ---- B fragment bases (direct-from-global) ----
  int NKT = K >> 5;
  int K0  = k_beg >> 5;
  const bf16* bp[2];
#pragma unroll
  for (int ni = 0; ni < 2; ++ni) {
    int g = (bn >> 5) + wn * 2 + ni;
    bp[ni] = Bf + ((size_t)(g * NKT + K0) * 2) * 512 + lane * 8;
  }

  bf16x8 ra0 = *(const bf16x8*)(gA);
  bf16x8 ra1 = *(const bf16x8*)(gA + (size_t)16 * K);
  bf16x8 bf00 = *(const bf16x8*)(bp[0]);
  bf16x8 bf01 = *(const bf16x8*)(bp[1]);
  bf16x8 bf10 = *(const bf16x8*)(bp[0] + 512);
  bf16x8 bf11 = *(const bf16x8*)(bp[1] + 512);

  f32x16 acc[4][2];
#pragma unroll
  for (int mi = 0; mi < 4; ++mi)
#pragma unroll
    for (int ni = 0; ni < 2; ++ni)
#pragma unroll
      for (int r = 0; r < 16; ++r) acc[mi][ni][r] = 0.f;

  int NT = KS >> 5;
  for (int t = 0; t < NT; ++t) {
    bf16* dA = &lds[(t & 1) * 8192];
    *(bf16x8*)(dA + wrE)       = ra0;
    *(bf16x8*)(dA + wrE + 128) = ra1;   // +16 rows (bits<7 unaffected by +128)
    bf16x8 nb00, nb01, nb10, nb11;
    if (t + 1 < NT) {                   // prefetch tile t+1
      size_t ko = (size_t)(t + 1) * 32;
      ra0 = *(const bf16x8*)(gA + ko);
      ra1 = *(const bf16x8*)(gA + ko + (size_t)16 * K);
      size_t bo_ = (size_t)(t + 1) * 1024;
      nb00 = *(const bf16x8*)(bp[0] + bo_);
      nb01 = *(const bf16x8*)(bp[1] + bo_);
      nb10 = *(const bf16x8*)(bp[0] + bo_ + 512);
      nb11 = *(const bf16x8*)(bp[1] + bo_ + 512);
    }
    __builtin_amdgcn_sched_barrier(0);
    asm volatile("s_waitcnt lgkmcnt(0)" ::: "memory");   // own ds_writes done
    __builtin_amdgcn_s_barrier();
    __builtin_amdgcn_sched_barrier(0);

    const bf16* bufA = &lds[(t & 1) * 8192];
    bf16x8 af[2][4];
#pragma unroll
    for (int ks = 0; ks < 2; ++ks)
#pragma unroll
      for (int mi = 0; mi < 4; ++mi) {
        int g2 = (wm * 4 + mi) * 2 + ks;
        af[ks][mi] = *(const bf16x8*)&bufA[g2 * 512 + ((g2 & 1) ? lrO : lrE)];
      }
    __builtin_amdgcn_s_setprio(1);
#pragma unroll
    for (int mi = 0; mi < 4; ++mi) {
      acc[mi][0] = __builtin_amdgcn_mfma_f32_32x32x16_bf16(af[0][mi], bf00, acc[mi][0], 0, 0, 0);
      acc[mi][1] = __builtin_amdgcn_mfma_f32_32x32x16_bf16(af[0][mi], bf01, acc[mi][1], 0, 0, 0);
    }
#pragma unroll
    for (int mi = 0; mi < 4; ++mi) {
      acc[mi][0] = __builtin_amdgcn_mfma_f32_32x32x16_bf16(af[1][mi], bf10, acc[mi][0], 0, 0, 0);
      acc[mi][1] = __builtin_amdgcn_mfma_f32_32x32x16_bf16(af[1][mi], bf11, acc[mi][1], 0, 0, 0);
    }
    __builtin_amdgcn_s_setprio(0);
    if (t + 1 < NT) { bf00 = nb00; bf01 = nb01; bf10 = nb10; bf11 = nb11; }
  }

  // ---- epilogues (C: col = l31 of B-frag, row = (reg&3)+8*(reg>>2)+4*kb) ----
  if (MODE == MODE_PART) {
    bf16* dst = (bf16*)outp + (size_t)blockIdx.z * M * N;
#pragma unroll
    for (int mi = 0; mi < 4; ++mi)
#pragma unroll
      for (int ni = 0; ni < 2; ++ni) {
        int col = bn + wn * 64 + ni * 32 + l31;
#pragma unroll
        for (int reg = 0; reg < 16; ++reg) {
          int row = bm + wm * 128 + mi * 32 + (reg & 3) + 8 * (reg >> 2) + 4 * kb;
          dst[(size_t)row * N + col] = __float2bfloat16(acc[mi][ni][reg]);
        }
      }
  } else if (MODE == MODE_GELU) {
    float bcol[2];
#pragma unroll
    for (int ni = 0; ni < 2; ++ni) bcol[ni] = bias[bn + wn * 64 + ni * 32 + l31];
#pragma unroll
    for (int mi = 0; mi < 4; ++mi)
#pragma unroll
      for (int ni = 0; ni < 2; ++ni) {
        int col = bn + wn * 64 + ni * 32 + l31;
#pragma unroll
        for (int reg = 0; reg < 16; ++reg) {
          int row = bm + wm * 128 + mi * 32 + (reg & 3) + 8 * (reg >> 2) + 4 * kb;
          ((bf16*)outp)[(size_t)row * N + col] =
              __float2bfloat16(gelu_f(acc[mi][ni][reg] + bcol[ni]));
        }
      }
  } else {  // MODE_QKV: seg block-uniform; q -> (b,h,t,d); k -> Kf frag; v -> Vf frag
    int seg = bn >> 10;
    int c1b = (bn & (NC - 1)) + wn * 64;
    const float* bpb = (seg == 0) ? bias : (seg == 1) ? bias2 : bias3;
    float bcol[2]; int hh[2], dd[2];
#pragma unroll
    for (int ni = 0; ni < 2; ++ni) {
      int c1 = c1b + ni * 32 + l31;
      bcol[ni] = bpb[c1]; hh[ni] = c1 >> 6; dd[ni] = c1 & (HD - 1);
    }
    if (seg == 0) {
      bf16* dst = (bf16*)outp;
#pragma unroll
      for (int mi = 0; mi < 4; ++mi)
#pragma unroll
        for (int reg = 0; reg < 16; ++reg) {
          int row = bm + wm * 128 + mi * 32 + (reg & 3) + 8 * (reg >> 2) + 4 * kb;
          int bbi = row >> 11, t = row & (TSEQ - 1);
#pragma unroll
          for (int ni = 0; ni < 2; ++ni)
            dst[((size_t)(bbi * NH + hh[ni]) * TSEQ + t) * HD + dd[ni]] =
                __float2bfloat16(acc[mi][ni][reg] + bcol[ni]);
        }
    } else if (seg == 1) {
      // Kf[bh][kt(64)][ds(4)][lane(64)][8]
      bf16* dst = (bf16*)out2;
#pragma unroll
      for (int mi = 0; mi < 4; ++mi)
#pragma unroll
        for (int reg = 0; reg < 16; ++reg) {
          int row = bm + wm * 128 + mi * 32 + (reg & 3) + 8 * (reg >> 2) + 4 * kb;
          int bbi = row >> 11, t = row & (TSEQ - 1);
          int kt = t >> 5, lk = t & 31;
#pragma unroll
          for (int ni = 0; ni < 2; ++ni) {
            int d = dd[ni];
            size_t off = ((((size_t)(bbi * NH + hh[ni]) * 64 + kt) * 4 + (d >> 4)) * 64
                          + ((d >> 3) & 1) * 32 + lk) * 8 + (d & 7);
            dst[off] = __float2bfloat16(acc[mi][ni][reg] + bcol[ni]);
          }
        }
    } else {
      // Vf[bh][kt(64)][dt(2)][ks(2)][lane(64)][8]
      bf16* dst = (bf16*)out3;
#pragma unroll
      for (int mi = 0; mi < 4; ++mi)
#pragma unroll
        for (int reg = 0; reg < 16; ++reg) {
          int row = bm + wm * 128 + mi * 32 + (reg & 3) + 8 * (reg >> 2) + 4 * kb;
          int bbi = row >> 11, t = row & (TSEQ - 1);
          int kt = t >> 5, rem = t & 31;
          int ks = rem >> 4, hf = (rem >> 3) & 1, j = rem & 7;
#pragma unroll
          for (int ni = 0; ni < 2; ++ni) {
            int d = dd[ni];
            size_t off = (((((size_t)(bbi * NH + hh[ni]) * 64 + kt) * 2 + (d >> 5)) * 2 + ks) * 64
                          + hf * 32 + (d & 31)) * 8 + j;
            dst[off] = __float2bfloat16(acc[mi][ni][reg] + bcol[ni]);
          }
        }
    }
  }
}

// ---------------- Flash attention v6: swapped-QK^T 32x32, split-K x4, frag-layout K/V ----
__global__ __launch_bounds__(256)
void attn_kernel(const bf16* __restrict__ q, const bf16* __restrict__ kf,
                 const bf16* __restrict__ vf, bf16* __restrict__ out) {
  int id  = blockIdx.x;            // 0..2047
  int xcd = id & 7;
  int t   = id >> 3;               // per-XCD arrival index 0..255
  int bh  = xcd * 4 + (t & 3);
  int u   = t >> 2;                // 0..63
  int qt  = (u < 32) ? (2 * u) : (63 - 2 * (u - 32));
  int b = bh >> 4, h = bh & 15;

  int tid  = threadIdx.x;
  int w    = tid >> 6;             // split-K wave 0..3
  int lane = tid & 63;
  int l31  = lane & 31;
  int hh   = lane >> 5;            // 0/1
  int h8   = hh * 8;
  int base4 = hh * 4;

  const bf16* qp  = q  + (size_t)(b * NH + h) * TSEQ * HD;
  const bf16* kfb = kf + (size_t)bh * (64 * 4 * 64 * 8);   // 256KB per (b,h)
  const bf16* vfb = vf + (size_t)bh * (64 * 2 * 2 * 64 * 8);

  int q0 = qt * 32;

  // Q fragments (B-operand): lane holds Q[q0+l31][ds*16 + h8 .. +7]
  bf16x8 qf[4];
#pragma unroll
  for (int ds = 0; ds < 4; ++ds)
    qf[ds] = *(const bf16x8*)(qp + (size_t)(q0 + l31) * HD + ds * 16 + h8);

  f32x16 o0, o1;
#pragma unroll
  for (int r = 0; r < 16; ++r) { o0[r] = 0.f; o1[r] = 0.f; }
  float lacc = 0.f;

  bf16x8 a0, a1, a2, a3;           // K fragments (A-operand), pipelined

  auto step = [&](int kt, bool dg) {
    const bf16* vs = vfb + (size_t)kt * 2048 + lane * 8;
    bf16x8 v00 = *(const bf16x8*)(vs);            // dt0 ks0
    bf16x8 v01 = *(const bf16x8*)(vs + 512);      // dt0 ks1
    bf16x8 v10 = *(const bf16x8*)(vs + 1024);     // dt1 ks0
    bf16x8 v11 = *(const bf16x8*)(vs + 1536);     // dt1 ks1
    bf16x8 n0, n1, n2, n3;
    bool pf = !dg && (kt + 4 <= qt);
    if (pf) {
      const bf16* kn = kfb + (size_t)(kt + 4) * 2048 + lane * 8;
      n0 = *(const bf16x8*)(kn);
      n1 = *(const bf16x8*)(kn + 512);
      n2 = *(const bf16x8*)(kn + 1024);
      n3 = *(const bf16x8*)(kn + 1536);
    }

    f32x16 c;
#pragma unroll
    for (int r = 0; r < 16; ++r) c[r] = 0.f;
    c = __builtin_amdgcn_mfma_f32_32x32x16_bf16(a0, qf[0], c, 0, 0, 0);
    c = __builtin_amdgcn_mfma_f32_32x32x16_bf16(a1, qf[1], c, 0, 0, 0);
    c = __builtin_amdgcn_mfma_f32_32x32x16_bf16(a2, qf[2], c, 0, 0, 0);
    c = __builtin_amdgcn_mfma_f32_32x32x16_bf16(a3, qf[3], c, 0, 0, 0);

    float p[16];
    float ls = 0.f;
#pragma unroll
    for (int r = 0; r < 16; ++r) {
      float pv = exp2f(fmaf(c[r], 0.18033688011112042f, -11.541560327111707f));
      if (dg) {
        int krr = (r & 3) + 8 * (r >> 2) + base4;
        pv = (krr <= l31) ? pv : 0.f;
      }
      p[r] = pv;
      ls += pv;
    }
    lacc += ls;

    unsigned A0 = cvtpk(p[0],  p[1]),  C0 = cvtpk(p[4],  p[5]);
    unsigned B0 = cvtpk(p[2],  p[3]),  D0 = cvtpk(p[6],  p[7]);
    pl32swap(A0, C0); pl32swap(B0, D0);
    unsigned A1 = cvtpk(p[8],  p[9]),  C1 = cvtpk(p[12], p[13]);
    unsigned B1 = cvtpk(p[10], p[11]), D1 = cvtpk(p[14], p[15]);
    pl32swap(A1, C1); pl32swap(B1, D1);
    u32x4 w0v = {A0, B0, C0, D0};
    u32x4 w1v = {A1, B1, C1, D1};
    bf16x8 pa0 = __builtin_bit_cast(bf16x8, w0v);
    bf16x8 pa1 = __builtin_bit_cast(bf16x8, w1v);

    o0 = __builtin_amdgcn_mfma_f32_32x32x16_bf16(pa0, v00, o0, 0, 0, 0);
    o0 = __builtin_amdgcn_mfma_f32_32x32x16_bf16(pa1, v01, o0, 0, 0, 0);
    o1 = __builtin_amdgcn_mfma_f32_32x32x16_bf16(pa0, v10, o1, 0, 0, 0);
    o1 = __builtin_amdgcn_mfma_f32_32x32x16_bf16(pa1, v11, o1, 0, 0, 0);

    if (pf) { a0 = n0; a1 = n1; a2 = n2; a3 = n3; }
  };

  if (w <= qt) {
    const bf16* ka = kfb + (size_t)w * 2048 + lane * 8;
    a0 = *(const bf16x8*)(ka);
    a1 = *(const bf16x8*)(ka + 512);
    a2 = *(const bf16x8*)(ka + 1024);
    a3 = *(const bf16x8*)(ka + 1536);
    int diag = (w == (qt & 3)) ? 1 : 0;   // diag implies w <= qt
    int T = ((qt - w) >> 2) + 1 - diag;   // non-diag step count
    int kt = w;
    for (int i = 0; i < T; ++i, kt += 4) step(kt, false);
    if (diag) step(qt, true);
  }

  // ---- cross-wave combine: 2-round LDS tree (33-float stride: conflict-free) ----
  __shared__ float red[2][64][33];
  auto dump = [&](int slot) {
    float* d = &red[slot][lane][0];
#pragma unroll
    for (int r = 0; r < 16; ++r) { d[r] = o0[r]; d[16 + r] = o1[r]; }
    d[32] = lacc;
  };
  auto gather = [&](int slot) {
    const float* s = &red[slot][lane][0];
#pragma unroll
    for (int r = 0; r < 16; ++r) { o0[r] += s[r]; o1[r] += s[16 + r]; }
    lacc += s[32];
  };
  if (w >= 2) dump(w - 2);
  __syncthreads();
  if (w < 2) gather(w);
  __syncthreads();
  if (w == 1) dump(0);
  __syncthreads();
  if (w == 0) {
    gather(0);
    float ltot = lacc + __shfl_xor(lacc, 32);
    float linv = 1.0f / ltot;
#pragma unroll
    for (int r = 0; r < 16; ++r) {
      int qoff = (r & 3) + 8 * (r >> 2) + base4;
      float sc = __shfl(linv, qoff);
      size_t ob = ((size_t)(b * TSEQ + q0 + qoff)) * NC + h * HD + l31;
      out[ob]      = __float2bfloat16(o0[r] * sc);
      out[ob + 32] = __float2bfloat16(o1[r] * sc);
    }
  }
}

extern "C" void kernel_launch(void* const* d_in, const int* in_sizes, int n_in,
                              void* d_out, int out_size, void* d_ws, size_t ws_size,
                              hipStream_t stream) {
  const float* x     = (const float*)d_in[0];
  const float* ln1_g = (const float*)d_in[1];
  const float* ln1_b = (const float*)d_in[2];
  const float* Wq    = (const float*)d_in[3];
  const float* bq    = (const float*)d_in[4];
  const float* Wk    = (const float*)d_in[5];
  const float* bk    = (const float*)d_in[6];
  const float* Wv    = (const float*)d_in[7];
  const float* bv    = (const float*)d_in[8];
  const float* Wo    = (const float*)d_in[9];
  const float* bo    = (const float*)d_in[10];
  const float* ln2_g = (const float*)d_in[11];
  const float* ln2_b = (const float*)d_in[12];
  const float* W1    = (const float*)d_in[13];
  const float* b1    = (const float*)d_in[14];
  const float* W2    = (const float*)d_in[15];
  const float* b2    = (const float*)d_in[16];

  char* ws = (char*)d_ws;
  const size_t MB = 1u << 20;
  bf16* WqkvT = (bf16*)(ws + 0 * MB);   // 4x1024x1024 (q|k|v|o) frag layout
  bf16* W1T  = (bf16*)(ws + 8 * MB);    // 4096x1024 frag
  bf16* W2T  = (bf16*)(ws + 16 * MB);   // 1024x4096 frag
  bf16* xn1  = (bf16*)(ws + 24 * MB);   // 4096x1024
  bf16* qb   = (bf16*)(ws + 32 * MB);   // (b,h,t,d)        [dead after attn]
  bf16* kfB  = (bf16*)(ws + 40 * MB);   // K fragment layout [dead after attn]
  bf16* vfB  = (bf16*)(ws + 48 * MB);   // V fragment layout [dead after attn]
  bf16* att  = (bf16*)(ws + 56 * MB);   // 4096x1024        [dead after Wo gemm]
  float* x2  = (float*)(ws + 64 * MB);  // 4096x1024 fp32
  bf16* xn2  = (bf16*)(ws + 80 * MB);   // 4096x1024
  bf16* h1   = (bf16*)(ws + 88 * MB);   // 4096x4096        [written after woP consumed]
  bf16* woP  = (bf16*)(ws + 88 * MB);   // 2x 4096x1024 Wo partials (reuses h1 region)
  bf16* w2P  = (bf16*)(ws + 32 * MB);   // 4x 4096x1024 W2 partials (reuses q/k/v/att)
  bf16* WoT  = WqkvT + 3 * (size_t)NC * NC;

  transpose_all_kernel<<<12288, dim3(32, 8), 0, stream>>>(
      Wq, Wk, Wv, Wo, W1, W2, WqkvT, W1T, W2T);

  ln_cast_kernel<<<NROWS, 256, 0, stream>>>(x, ln1_g, ln1_b, xn1);

  gemm256<MODE_QKV><<<dim3(12, 16, 1), 512, 0, stream>>>(
      xn1, WqkvT, bq, bk, bv, qb, kfB, vfB, NROWS, 3 * NC, NC, NC);

  attn_kernel<<<2048, 256, 0, stream>>>(qb, kfB, vfB, att);

  gemm256<MODE_PART><<<dim3(4, 16, 2), 512, 0, stream>>>(
      att, WoT, nullptr, nullptr, nullptr, woP, nullptr, nullptr, NROWS, NC, NC, NC / 2);

  wo_ln_kernel<<<NROWS, 256, 0, stream>>>(x, bo, woP, ln2_g, ln2_b, x2, xn2);

  gemm256<MODE_GELU><<<dim3(16, 16, 1), 512, 0, stream>>>(
      xn2, W1T, b1, nullptr, nullptr, h1, nullptr, nullptr, NROWS, DFF, NC, NC);

  gemm256<MODE_PART><<<dim3(4, 16, 4), 512, 0, stream>>>(
      h1, W2T, nullptr, nullptr, nullptr, w2P, nullptr, nullptr, NROWS, NC, DFF, DFF / 4);

  w2_final_kernel<<<NROWS, 256, 0, stream>>>(x2, b2, w2P, (float*)d_out);
}